// Round 8
// baseline (261.949 us; speedup 1.0000x reference)
//
#include <hip/hip_runtime.h>
#include <math.h>

namespace {

constexpr int NQ  = 6000;   // fluid particles (queries)
constexpr int NB  = 3000;   // box particles
constexpr int K   = 80;     // neighbor cap
constexpr float RAD = 0.1125f;
constexpr float RADI = 1.0f / 0.1125f;   // reciprocal (1-ulp vs divide; << bf16 noise)
constexpr float R2  = RAD * RAD;
constexpr float EPSF = 1e-12f;

constexpr int GS  = 8;           // grid dim (cell 0.125 >= RADIUS)
constexpr int NC  = GS*GS*GS;    // 512 cells
constexpr int NO  = 65 * 64;     // G row: 64 cells + 1 dense-skip col, O=64
constexpr int NBLK = (NQ + 3) / 4;            // gather blocks (4 queries each)
constexpr int NBLK8 = ((NBLK + 7) / 8) * 8;   // padded for XCD swizzle
constexpr int PREPB = 512;       // prep blocks fused into nn2gc launch
constexpr int YST = 260;         // Y row stride: 65 cells x 4 floats (padded)

typedef __attribute__((ext_vector_type(8))) short bf16x8;
typedef __attribute__((ext_vector_type(4))) float f32x4;

__device__ __forceinline__ float sgn(float x) {
    return (x > 0.f) ? 1.f : ((x < 0.f) ? -1.f : 0.f);
}

__device__ __forceinline__ unsigned int bf16rne(float f) {
    unsigned int u = __float_as_uint(f);
    return (u + 0x7fffu + ((u >> 16) & 1u)) >> 16;   // round-to-nearest-even
}
__device__ __forceinline__ float bf16f(unsigned short u) {
    return __uint_as_float(((unsigned int)u) << 16);
}
__device__ __forceinline__ int cell_of(float x, float y, float z) {
    int cx = min(max((int)(x * (float)GS), 0), GS-1);
    int cy = min(max((int)(y * (float)GS), 0), GS-1);
    int cz = min(max((int)(z * (float)GS), 0), GS-1);
    return (cz*GS + cy)*GS + cx;
}

// ball->cube + trilinear coefs from raw delta (ddx = pj - q), store at slot.
// Runs DENSE (phase 2): all lanes active, one execution per slot.
__device__ __forceinline__ void coef_compute(
    float ddx, float ddy, float ddz, int slot,
    int* __restrict__ cells, float* __restrict__ coefs)
{
    float rx = ddx * RADI, ry = ddy * RADI, rz = ddz * RADI;
    float r2 = rx*rx + ry*ry + rz*rz;
    float w1 = 1.f - r2;
    float win = (w1 > 0.f) ? w1*w1*w1 : 0.f;   // clip((1-r2)^3, 0, 1)
    float norm = sqrtf(r2);
    float rxy2 = rx*rx + ry*ry;
    float xc, yc, zc;
    if (r2 < 1e-12f) {
        xc = yc = zc = 0.f;
    } else if (1.25f * rz * rz > rxy2) {
        float s = sqrtf(3.0f * norm / (norm + fabsf(rz) + EPSF));
        xc = s * rx; yc = s * ry; zc = sgn(rz) * norm;
    } else {
        float s = norm / sqrtf(rxy2 + EPSF);
        xc = s * rx; yc = s * ry; zc = 1.5f * rz * s;
    }
    float rxy = sqrtf(xc*xc + yc*yc);
    const float FP = (float)(4.0 / M_PI);
    float u, v;
    if (rxy < EPSF) {
        u = 0.f; v = 0.f;
    } else if (fabsf(xc) >= fabsf(yc)) {
        float sx = (fabsf(xc) < EPSF) ? EPSF : xc;
        u = sgn(xc) * rxy;
        v = u * FP * atanf(yc / sx);
    } else {
        float sy = (fabsf(yc) < EPSF) ? EPSF : yc;
        v = sgn(yc) * rxy;
        u = v * FP * atanf(xc / sy);
    }
    float gx = fminf(fmaxf((u  + 1.f) * 0.5f * 3.f, 0.f), 3.f);
    float gy = fminf(fmaxf((v  + 1.f) * 0.5f * 3.f, 0.f), 3.f);
    float gz = fminf(fmaxf((zc + 1.f) * 0.5f * 3.f, 0.f), 3.f);
    int ix = min((int)floorf(gx), 2);
    int iy = min((int)floorf(gy), 2);
    int iz = min((int)floorf(gz), 2);
    float tx = gx - (float)ix, ty = gy - (float)iy, tz = gz - (float)iz;
    cells[slot] = iz*16 + iy*4 + ix;
    float wx0 = 1.f - tx, wy0 = 1.f - ty, wz0 = 1.f - tz;
    // c = dx*4 + dy*2 + dz (python loop order)
    float4 lo, hi;
    lo.x = wx0 * wy0 * wz0 * win;   // c0: (0,0,0)
    lo.y = wx0 * wy0 * tz  * win;   // c1: (0,0,1)
    lo.z = wx0 * ty  * wz0 * win;   // c2: (0,1,0)
    lo.w = wx0 * ty  * tz  * win;   // c3: (0,1,1)
    hi.x = tx  * wy0 * wz0 * win;   // c4: (1,0,0)
    hi.y = tx  * wy0 * tz  * win;   // c5: (1,0,1)
    hi.z = tx  * ty  * wz0 * win;   // c6: (1,1,0)
    hi.w = tx  * ty  * tz  * win;   // c7: (1,1,1)
    float4* cf = (float4*)(coefs + (size_t)slot * 8);
    cf[0] = lo; cf[1] = hi;
}

// ---- grid build: count + scans + SCATTER, one single-block kernel -----------
// Cursors live in LDS (reuse the count arrays); saves a dispatch + cur globals.
__global__ __launch_bounds__(1024) void grid_build_kernel(
    const float* __restrict__ pos, const float* __restrict__ box,
    int* __restrict__ gs_f, int* __restrict__ gs_b,
    float* __restrict__ spf, int* __restrict__ sif,
    float* __restrict__ spb, int* __restrict__ sib)
{
    __shared__ int cntF[NC], cntB[NC];
    __shared__ int tmpF[NC], tmpB[NC];
    int tid = threadIdx.x;
    int half = tid >> 9, t = tid & 511;
    if (half == 0) cntF[t] = 0; else cntB[t] = 0;
    __syncthreads();
    for (int i = tid; i < NQ + NB; i += 1024) {
        if (i < NQ) {
            atomicAdd(&cntF[cell_of(pos[i*3], pos[i*3+1], pos[i*3+2])], 1);
        } else {
            int b = i - NQ;
            atomicAdd(&cntB[cell_of(box[b*3], box[b*3+1], box[b*3+2])], 1);
        }
    }
    __syncthreads();
    // parallel Hillis-Steele scans: threads 0-511 fluid, 512-1023 box
    int* cnt = half ? cntB : cntF;
    int* tmp = half ? tmpB : tmpF;
    int cv = cnt[t];
    tmp[t] = cv;
    __syncthreads();
    for (int off = 1; off < NC; off <<= 1) {
        int v = (t >= off) ? tmp[t - off] : 0;
        __syncthreads();
        tmp[t] += v;
        __syncthreads();
    }
    int* gsd = half ? gs_b : gs_f;
    int excl = tmp[t] - cv;
    gsd[t] = excl;
    cnt[t] = excl;                       // reuse count array as LDS cursor
    if (t == NC - 1) gsd[NC] = tmp[t];
    __syncthreads();
    // scatter points into cell-sorted float4 arrays (LDS-atomic cursors)
    for (int i = tid; i < NQ + NB; i += 1024) {
        if (i < NQ) {
            float x = pos[i*3], y = pos[i*3+1], z = pos[i*3+2];
            int dst = atomicAdd(&cntF[cell_of(x,y,z)], 1);
            *reinterpret_cast<float4*>(spf + (size_t)dst*4) = make_float4(x, y, z, 0.f);
            sif[dst] = i;
        } else {
            int b = i - NQ;
            float x = box[b*3], y = box[b*3+1], z = box[b*3+2];
            int dst = atomicAdd(&cntB[cell_of(x,y,z)], 1);
            *reinterpret_cast<float4*>(spb + (size_t)dst*4) = make_float4(x, y, z, 0.f);
            sib[dst] = b;
        }
    }
}

// -------- fused: [blocks 0..PREPB) heavy prep  |  [PREPB..) neighbor search --
__global__ __launch_bounds__(256) void nn2gc_kernel(
    const float* __restrict__ pos,
    const float* __restrict__ spf, const int* __restrict__ sif, const int* __restrict__ gsf,
    const float* __restrict__ spb, const int* __restrict__ sib, const int* __restrict__ gsb,
    int* __restrict__ f_cnt, int* __restrict__ f_idx, float* __restrict__ f_d2,
    int* __restrict__ f_cell, float* __restrict__ f_coef,
    int* __restrict__ b_cnt, int* __restrict__ b_idx, float* __restrict__ b_d2,
    int* __restrict__ b_cell, float* __restrict__ b_coef,
    // prep args:
    const float* __restrict__ c1w, const float* __restrict__ d1w,
    const float* __restrict__ c2w, const float* __restrict__ d2w,
    const float* __restrict__ c3w, const float* __restrict__ d3w,
    const float* __restrict__ vel, const float* __restrict__ bfeat,
    const float* __restrict__ cfw, const float* __restrict__ cow,
    const float* __restrict__ d0w, const float* __restrict__ d0b,
    unsigned short* __restrict__ Bt1, unsigned short* __restrict__ Bt2,
    unsigned short* __restrict__ G0f, unsigned short* __restrict__ G0b,
    float* __restrict__ W3p, float* __restrict__ x1)
{
    if (blockIdx.x < PREPB) {
        int stride = PREPB * 256;
        int gid = blockIdx.x * 256 + threadIdx.x;
        // G0f[j, c*32+o] = [1,vel_j] . cf_w[c,:,o]   (bf16, 2 o's per iter)
        for (int i = gid; i < NQ * 1024; i += stride) {
            int j = i >> 10, rr = i & 1023, c = rr >> 4, op = (rr & 15) * 2;
            float vx = vel[j*3+0], vy = vel[j*3+1], vz = vel[j*3+2];
            const float* w = cfw + (size_t)c * 128;    // cf_w[c][f][o], f-stride 32
            float s0 = w[op]   + vx*w[32+op]   + vy*w[64+op]   + vz*w[96+op];
            float s1 = w[op+1] + vx*w[32+op+1] + vy*w[64+op+1] + vz*w[96+op+1];
            *reinterpret_cast<unsigned int*>(G0f + (size_t)j * 2048 + c*32 + op) =
                bf16rne(s0) | (bf16rne(s1) << 16);
        }
        // G0b[j, c*32+o] = bfeat_j . co_w[c,:,o]
        for (int i = gid; i < NB * 1024; i += stride) {
            int j = i >> 10, rr = i & 1023, c = rr >> 4, op = (rr & 15) * 2;
            float b0 = bfeat[j*3+0], b1 = bfeat[j*3+1], b2 = bfeat[j*3+2];
            const float* w = cow + (size_t)c * 96;     // co_w[c][f][o], f-stride 32
            float s0 = b0*w[op]   + b1*w[32+op]   + b2*w[64+op];
            float s1 = b0*w[op+1] + b1*w[32+op+1] + b2*w[64+op+1];
            *reinterpret_cast<unsigned int*>(G0b + (size_t)j * 2048 + c*32 + op) =
                bf16rne(s0) | (bf16rne(s1) << 16);
        }
        for (int i = gid; i < NO * 96; i += stride) {   // Bt1[n,f]; n = c*64+o
            int n = i / 96, f = i % 96, c = n >> 6, o = n & 63;
            float v = (c < 64) ? c1w[((size_t)c*96 + f)*64 + o] : d1w[f*64 + o];
            Bt1[i] = (unsigned short)bf16rne(v);
        }
        for (int i = gid; i < NO * 64; i += stride) {
            int n = i / 64, f = i % 64, c = n >> 6, o = n & 63;
            float v = (c < 64) ? c2w[((size_t)c*64 + f)*64 + o] : d2w[f*64 + o];
            Bt2[i] = (unsigned short)bf16rne(v);
        }
        for (int i = gid; i < 64 * 195; i += stride) {   // W3p[f][c*3+o]
            int f = i / 195, r = i % 195, c = r / 3, o = r % 3;
            W3p[i] = (c < 64) ? c3w[(c*64 + f)*3 + o] : d3w[f*3 + o];
        }
        for (int i = gid; i < NQ * 32; i += stride) {    // dense-0 -> x1[:,64:96]
            int n = i >> 5, o = i & 31;
            float acc = d0b[o] + d0w[o]
                      + vel[n*3+0] * d0w[32 + o]
                      + vel[n*3+1] * d0w[64 + o]
                      + vel[n*3+2] * d0w[96 + o];
            x1[n*96 + 64 + o] = acc;
        }
        return;
    }
    int gw = (int)(blockIdx.x - PREPB) * 4 + ((int)threadIdx.x >> 6);
    int lane = threadIdx.x & 63;
    if (gw >= 2 * NQ) return;
    bool isF = gw < NQ;
    int wid = isF ? gw : gw - NQ;
    const float* sp = isF ? spf : spb;
    const int*   si = isF ? sif : sib;
    const int*   gs = isF ? gsf : gsb;
    int*   cnt   = isF ? f_cnt  : b_cnt;
    int*   idxs  = isF ? f_idx  : b_idx;
    float* d2s   = isF ? f_d2   : b_d2;
    int*   cells = isF ? f_cell : b_cell;
    float* coefs = isF ? f_coef : b_coef;
    int    tot   = isF ? NQ : NB;
    float qx = pos[wid*3+0], qy = pos[wid*3+1], qz = pos[wid*3+2];
    int cx = min(max((int)(qx * (float)GS), 0), GS-1);
    int cy = min(max((int)(qy * (float)GS), 0), GS-1);
    int cz = min(max((int)(qz * (float)GS), 0), GS-1);
    int x0 = max(cx-1, 0), x1c = min(cx+1, GS-1);
    int base = wid * K;
    int c = 0;

    auto process = [&](bool hit, int oj, float ddx, float ddy, float ddz, float d2) {
        unsigned long long m = __ballot(hit);
        int pc = __popcll(m);
        if (pc == 0) return;
        if (c + pc <= K) {
            if (hit) {
                int p = c + __popcll(m & ((1ull << lane) - 1ull));
                idxs[base + p] = oj;
                d2s [base + p] = d2;
                float* cf = coefs + (size_t)(base + p) * 8;
                cf[0] = ddx; cf[1] = ddy; cf[2] = ddz;   // deltas; coefs in phase 2
            }
            c += pc;
        } else {
            // rare overflow: keep the K nearest (top_k semantics)
            while (m) {
                int l = __ffsll((unsigned long long)m) - 1;
                m &= m - 1ull;
                float dd = __shfl(d2, l);
                int jv = __shfl(oj, l);
                float ax = __shfl(ddx, l), ay = __shfl(ddy, l), az = __shfl(ddz, l);
                int slot = -1;
                if (c < K) { slot = c; c++; }
                else {
                    float mx = -1.f; int am = 0;
                    for (int s = 0; s < K; ++s) {
                        float v = d2s[base + s];
                        if (v > mx) { mx = v; am = s; }
                    }
                    if (dd < mx) slot = am;
                }
                if (slot >= 0 && lane == 0) {
                    idxs[base + slot] = jv;
                    d2s [base + slot] = dd;
                    float* cf = coefs + (size_t)(base + slot) * 8;
                    cf[0] = ax; cf[1] = ay; cf[2] = az;
                }
            }
        }
    };

    // spans of all 9 (z,y) rows -- wave-uniform loads, issued together
    int s0v[9], s1v[9];
#pragma unroll
    for (int r = 0; r < 9; ++r) {
        int z = cz + (r / 3) - 1, y = cy + (r % 3) - 1;
        bool ok = ((unsigned)z < (unsigned)GS) && ((unsigned)y < (unsigned)GS);
        int row = ok ? (z*GS + y)*GS : 0;
        int a0 = gs[row + x0];
        int a1 = gs[row + x1c + 1];
        s0v[r] = a0;
        s1v[r] = ok ? a1 : a0;
    }
    // preload segment-0 candidate of every row (independent -> all in flight)
    int    ojv[9];
    float4 pv [9];
#pragma unroll
    for (int r = 0; r < 9; ++r) {
        int a = min(s0v[r] + lane, tot - 1);
        ojv[r] = si[a];
        pv [r] = *reinterpret_cast<const float4*>(sp + (size_t)a * 4);
    }
    // process the 9 rows from registers
#pragma unroll
    for (int r = 0; r < 9; ++r) {
        int ii = s0v[r] + lane;
        float ddx = pv[r].x - qx, ddy = pv[r].y - qy, ddz = pv[r].z - qz;
        float d2 = ddx*ddx + ddy*ddy + ddz*ddz;
        int oj = ojv[r];
        bool hit = (ii < s1v[r]) && (d2 <= R2) && !(isF && oj == wid);
        process(hit, oj, ddx, ddy, ddz, d2);
    }
    // rare tails: rows with more than 64 candidates
#pragma unroll
    for (int r = 0; r < 9; ++r) {
        for (int j0 = s0v[r] + 64; j0 < s1v[r]; j0 += 64) {
            int ii = j0 + lane;
            int a = min(ii, tot - 1);
            int oj = si[a];
            float4 p = *reinterpret_cast<const float4*>(sp + (size_t)a * 4);
            float ddx = p.x - qx, ddy = p.y - qy, ddz = p.z - qz;
            float d2 = ddx*ddx + ddy*ddy + ddz*ddz;
            bool hit = (ii < s1v[r]) && (d2 <= R2) && !(isF && oj == wid);
            process(hit, oj, ddx, ddy, ddz, d2);
        }
    }
    // phase 2: dense coef computation (one pass, all lanes active)
    for (int k2 = lane; k2 < c; k2 += 64) {
        const float4 d = *reinterpret_cast<const float4*>(coefs + (size_t)(base + k2) * 8);
        coef_compute(d.x, d.y, d.z, base + k2, cells, coefs);
    }
    if (lane == 0) cnt[wid] = c;
}

// ---- layer-0 gather (G-form): one block per query, 4 waves, two 32-lane
//      halves process 2 neighbors/iter. jcb = j*2048 + cell*32 precomputed. ---
__global__ __launch_bounds__(256) void gather0_kernel(
    const int* __restrict__ order,
    const int* __restrict__ f_cnt, const int* __restrict__ f_idx,
    const int* __restrict__ f_cell, const float* __restrict__ f_coef,
    const int* __restrict__ b_cnt, const int* __restrict__ b_idx,
    const int* __restrict__ b_cell, const float* __restrict__ b_coef,
    const unsigned short* __restrict__ G0f, const unsigned short* __restrict__ G0b,
    const float* __restrict__ cfb, const float* __restrict__ cob,
    float* __restrict__ x1)
{
    __shared__ __align__(16) float coefF[K * 8];
    __shared__ __align__(16) float coefB[K * 8];
    __shared__ int jF[K], jB[K];
    __shared__ float partF[8][32], partB[8][32];
    int lb = (blockIdx.x & 7) * (gridDim.x >> 3) + (blockIdx.x >> 3);  // XCD swizzle
    int tid = threadIdx.x;
    int wv = tid >> 6, lane = tid & 63;
    int h = lane >> 5, o = lane & 31;
    int r = wv * 2 + h;
    int n = order[lb];
    int cnf = f_cnt[n], cnb = b_cnt[n];
    {
        const float4* srcF = (const float4*)(f_coef + (size_t)n * K * 8);
        const float4* srcB = (const float4*)(b_coef + (size_t)n * K * 8);
        for (int i = tid; i < cnf * 2; i += 256) ((float4*)coefF)[i] = srcF[i];
        for (int i = tid; i < cnb * 2; i += 256) ((float4*)coefB)[i] = srcB[i];
        for (int i = tid; i < cnf; i += 256) jF[i] = f_idx[n*K + i] * 2048 + f_cell[n*K + i] * 32;
        for (int i = tid; i < cnb; i += 256) jB[i] = b_idx[n*K + i] * 2048 + b_cell[n*K + i] * 32;
    }
    __syncthreads();
    // c = dx*4+dy*2+dz ; cell = cbse + dz*16 + dy*4 + dx
    float af = 0.f;
#pragma unroll 2
    for (int k = r; k < cnf; k += 8) {
        const unsigned short* Gj = G0f + jF[k] + o;
        float4 cA = *reinterpret_cast<const float4*>(coefF + k*8);
        float4 cB = *reinterpret_cast<const float4*>(coefF + k*8 + 4);
        af += cA.x * bf16f(Gj[ 0 * 32]);
        af += cA.y * bf16f(Gj[16 * 32]);
        af += cA.z * bf16f(Gj[ 4 * 32]);
        af += cA.w * bf16f(Gj[20 * 32]);
        af += cB.x * bf16f(Gj[ 1 * 32]);
        af += cB.y * bf16f(Gj[17 * 32]);
        af += cB.z * bf16f(Gj[ 5 * 32]);
        af += cB.w * bf16f(Gj[21 * 32]);
    }
    float ab = 0.f;
#pragma unroll 2
    for (int k = r; k < cnb; k += 8) {
        const unsigned short* Gj = G0b + jB[k] + o;
        float4 cA = *reinterpret_cast<const float4*>(coefB + k*8);
        float4 cB = *reinterpret_cast<const float4*>(coefB + k*8 + 4);
        ab += cA.x * bf16f(Gj[ 0 * 32]);
        ab += cA.y * bf16f(Gj[16 * 32]);
        ab += cA.z * bf16f(Gj[ 4 * 32]);
        ab += cA.w * bf16f(Gj[20 * 32]);
        ab += cB.x * bf16f(Gj[ 1 * 32]);
        ab += cB.y * bf16f(Gj[17 * 32]);
        ab += cB.z * bf16f(Gj[ 5 * 32]);
        ab += cB.w * bf16f(Gj[21 * 32]);
    }
    partF[r][o] = af;
    partB[r][o] = ab;
    __syncthreads();
    if (tid < 64) {
        int oo = tid & 31;
        if (tid < 32) {
            float s = cfb[oo];
#pragma unroll
            for (int q = 0; q < 8; ++q) s += partF[q][oo];
            x1[(size_t)n * 96 + 32 + oo] = s;      // a_cf -> x1[:,32:64]
        } else {
            float s = cob[oo];
#pragma unroll
            for (int q = 0; q < 8; ++q) s += partB[q][oo];
            x1[(size_t)n * 96 + oo] = s;           // a_co -> x1[:,0:32]
        }
    }
}

// ---- MFMA G-GEMM: G[j, n] = relu(feats[j,:]) . Bt[n,:]  (bf16 in/out) -------
// A-tile staged ONCE per block; loops over NT n-tiles (65 = 13*5).
// C written via LDS transpose (aliasing Bs): 4 threads/row x 2 dwordx4 each
// -> full 64-short rows, coalesced.
template<int F>
__global__ __launch_bounds__(256) void gemmGm_kernel(
    const float* __restrict__ feats,            // [M,F] fp32
    const unsigned short* __restrict__ Bt,      // [NO,F] bf16 (n-major)
    unsigned short* __restrict__ G,             // [M,NO] bf16
    int M)
{
    constexpr int NT = 5;
    constexpr int AST = F + 8;
    constexpr int CST = 72;                     // C-tile stride (16B-aligned rows)
    __shared__ unsigned short As[64 * AST];     // [m][k]
    __shared__ unsigned short Bs[64 * AST];     // [n][k]  (aliased as C-tile)
    unsigned short* Cs = Bs;
    int tid = threadIdx.x, lane = tid & 63, wv = tid >> 6;
    int m0 = blockIdx.x * 64;
    int nt0 = blockIdx.y * NT;
    for (int i = tid; i < 64 * F / 4; i += 256) {
        int m = i / (F / 4), k4 = i % (F / 4);
        int gm = m0 + m; if (gm >= M) gm = M - 1;
        float4 av = *reinterpret_cast<const float4*>(feats + (size_t)gm * F + k4 * 4);
        uint2 ov;
        ov.x = bf16rne(fmaxf(av.x, 0.f)) | (bf16rne(fmaxf(av.y, 0.f)) << 16);
        ov.y = bf16rne(fmaxf(av.z, 0.f)) | (bf16rne(fmaxf(av.w, 0.f)) << 16);
        *reinterpret_cast<uint2*>(As + m * AST + k4 * 4) = ov;
    }
    int mr = lane & 15, quad = lane >> 4;
    int orow = tid >> 2, oseg = tid & 3;        // 4 threads/row, 16 shorts each
    for (int t = 0; t < NT; ++t) {
        int no0 = (nt0 + t) * 64;
        __syncthreads();   // prev tile's Cs reads done -> safe to stage Bs
        for (int i = tid; i < 64 * F / 8; i += 256) {
            int nn = i / (F / 8), k8 = i % (F / 8);
            *reinterpret_cast<uint4*>(Bs + nn * AST + k8 * 8) =
                *reinterpret_cast<const uint4*>(Bt + (size_t)(no0 + nn) * F + k8 * 8);
        }
        __syncthreads();   // Bs (and As on t=0) visible
        f32x4 acc[4] = {{0.f,0.f,0.f,0.f},{0.f,0.f,0.f,0.f},
                        {0.f,0.f,0.f,0.f},{0.f,0.f,0.f,0.f}};
#pragma unroll
        for (int kc = 0; kc < F; kc += 32) {
            bf16x8 a = *reinterpret_cast<const bf16x8*>(As + (wv*16 + mr) * AST + kc + quad*8);
#pragma unroll
            for (int q = 0; q < 4; ++q) {
                bf16x8 b = *reinterpret_cast<const bf16x8*>(Bs + (q*16 + mr) * AST + kc + quad*8);
                acc[q] = __builtin_amdgcn_mfma_f32_16x16x32_bf16(a, b, acc[q], 0, 0, 0);
            }
        }
        __syncthreads();   // all waves done READING Bs -> reuse as C-tile
        // C layout: col_local = q*16+mr, row_local = wv*16 + quad*4 + r
#pragma unroll
        for (int q = 0; q < 4; ++q)
#pragma unroll
            for (int rr = 0; rr < 4; ++rr)
                Cs[(wv*16 + quad*4 + rr) * CST + q*16 + mr] =
                    (unsigned short)bf16rne(acc[q][rr]);
        __syncthreads();   // C-tile ready
        int gm = m0 + orow;
        uint4 v0 = *reinterpret_cast<const uint4*>(Cs + orow * CST + oseg * 16);
        uint4 v1 = *reinterpret_cast<const uint4*>(Cs + orow * CST + oseg * 16 + 8);
        if (gm < M) {
            *reinterpret_cast<uint4*>(G + (size_t)gm * NO + no0 + oseg * 16)     = v0;
            *reinterpret_cast<uint4*>(G + (size_t)gm * NO + no0 + oseg * 16 + 8) = v1;
        }
    }
}

// ---- G-gather v2: ONE QUERY PER BLOCK, k-loop split across the 4 waves ------
// jcb = j*NO + cell*64 precomputed in LDS (shorter dependent address chain).
// FUSEY=1 additionally fuses Y = relu(x3) * W3p using all 256 threads
// (Y rows padded: 65 cells x 4 floats, stride YST).
template<int FUSEY>
__global__ __launch_bounds__(256) void gatherG_kernel(
    const int* __restrict__ order,
    const int* __restrict__ cnt, const int* __restrict__ nidx,
    const int* __restrict__ ncell, const float* __restrict__ ncoef,
    const unsigned short* __restrict__ G,
    const float* __restrict__ cb, const float* __restrict__ db,
    const float* __restrict__ resid, float* __restrict__ out,
    const float* __restrict__ W3p, float* __restrict__ Y)
{
    __shared__ __align__(16) float coefL[K * 8];   // 2.5 KB
    __shared__ int jL[K];
    __shared__ float part[3][64];
    __shared__ float xs[64];
    int lb = (blockIdx.x & 7) * (gridDim.x >> 3) + (blockIdx.x >> 3);  // XCD swizzle
    int tid = threadIdx.x;
    int wv = tid >> 6, lane = tid & 63;
    int n = order[lb];
    int cn = cnt[n];
    // cooperative staging: coefs (float4 x 2 per k), combined j*NO+cell*64
    {
        const float4* src = (const float4*)(ncoef + (size_t)n * K * 8);
        float4* dst = (float4*)coefL;
        for (int i = tid; i < cn * 2; i += 256) dst[i] = src[i];
        for (int i = tid; i < cn; i += 256)
            jL[i] = nidx[n*K + i] * NO + ncell[n*K + i] * 64;
    }
    __syncthreads();
    float a0 = 0.f, a1 = 0.f, a2 = 0.f, a3 = 0.f;
#pragma unroll 2
    for (int k = wv; k < cn; k += 4) {
        float4 cA = *reinterpret_cast<const float4*>(coefL + k*8);      // c=0..3 (dx=0)
        float4 cB = *reinterpret_cast<const float4*>(coefL + k*8 + 4);  // c=4..7 (dx=1)
        const unsigned short* Gj = G + jL[k] + lane;
        // c = dx*4+dy*2+dz ; cell = cbse + dz*16 + dy*4 + dx
        a0 += cA.x * bf16f(Gj[ 0 * 64]);
        a1 += cA.y * bf16f(Gj[16 * 64]);
        a2 += cA.z * bf16f(Gj[ 4 * 64]);
        a3 += cA.w * bf16f(Gj[20 * 64]);
        a0 += cB.x * bf16f(Gj[ 1 * 64]);
        a1 += cB.y * bf16f(Gj[17 * 64]);
        a2 += cB.z * bf16f(Gj[ 5 * 64]);
        a3 += cB.w * bf16f(Gj[21 * 64]);
    }
    float s = (a0 + a1) + (a2 + a3);
    if (wv > 0) part[wv - 1][lane] = s;
    __syncthreads();
    if (wv == 0) {
        float acc = cb[lane] + db[lane] + s
                  + part[0][lane] + part[1][lane] + part[2][lane];
        acc += bf16f(G[(size_t)n * NO + 64*64 + lane]);   // dense skip
        if (resid) acc += resid[(size_t)n * 64 + lane];
        if (!FUSEY) {
            out[(size_t)n * 64 + lane] = acc;
        } else {
            xs[lane] = fmaxf(acc, 0.f);
        }
    }
    if (FUSEY) {
        __syncthreads();
        // fused y3t: Y[n, c*4+o] = sum_f relu(x3[n,f]) * W3p[f, c*3+o]  (o<3)
        for (int idx = tid; idx < YST; idx += 256) {
            int cc = idx >> 2, o = idx & 3;
            if (o < 3) {
                float sum = 0.f;
#pragma unroll 16
                for (int f = 0; f < 64; ++f) sum += xs[f] * W3p[f*195 + cc*3 + o];
                Y[(size_t)n * YST + idx] = sum;
            }
        }
    }
}

// ---- layer-3 gather: lane = neighbor; corners load as aligned float4 pairs --
__global__ __launch_bounds__(256) void gather3_kernel(
    const int* __restrict__ order,
    const int* __restrict__ cnt, const int* __restrict__ nidx,
    const int* __restrict__ ncell, const float* __restrict__ ncoef,
    const float* __restrict__ Y,
    const float* __restrict__ cb3, const float* __restrict__ db3,
    float* __restrict__ out)
{
    int lb = (blockIdx.x & 7) * (gridDim.x >> 3) + (blockIdx.x >> 3);
    int gw = lb * 4 + ((int)threadIdx.x >> 6);
    int lane = threadIdx.x & 63;
    if (gw >= NQ) return;
    int n = order[gw];
    int cn = cnt[n];
    float a0 = 0.f, a1 = 0.f, a2 = 0.f;
#pragma unroll
    for (int seg = 0; seg < 2; ++seg) {
        int kidx = seg * 64 + lane;
        if (kidx < cn) {
            int j  = nidx [n*K + kidx];
            int cb = ncell[n*K + kidx];
            const float* cf = ncoef + (size_t)(n*K + kidx) * 8;
            float4 cA = *reinterpret_cast<const float4*>(cf);      // c=0..3 (dx=0)
            float4 cB = *reinterpret_cast<const float4*>(cf + 4);  // c=4..7 (dx=1)
            const float* Yj = Y + (size_t)j * YST + (size_t)cb * 4;
            // cell offsets {0,16,4,20} <-> cA.{x,y,z,w}; +1 (dx=1) <-> cB
            float4 v00 = *reinterpret_cast<const float4*>(Yj +  0 * 4);
            float4 v01 = *reinterpret_cast<const float4*>(Yj +  1 * 4);
            float4 v10 = *reinterpret_cast<const float4*>(Yj + 16 * 4);
            float4 v11 = *reinterpret_cast<const float4*>(Yj + 17 * 4);
            float4 v20 = *reinterpret_cast<const float4*>(Yj +  4 * 4);
            float4 v21 = *reinterpret_cast<const float4*>(Yj +  5 * 4);
            float4 v30 = *reinterpret_cast<const float4*>(Yj + 20 * 4);
            float4 v31 = *reinterpret_cast<const float4*>(Yj + 21 * 4);
            a0 += cA.x*v00.x + cB.x*v01.x + cA.y*v10.x + cB.y*v11.x
                + cA.z*v20.x + cB.z*v21.x + cA.w*v30.x + cB.w*v31.x;
            a1 += cA.x*v00.y + cB.x*v01.y + cA.y*v10.y + cB.y*v11.y
                + cA.z*v20.y + cB.z*v21.y + cA.w*v30.y + cB.w*v31.y;
            a2 += cA.x*v00.z + cB.x*v01.z + cA.y*v10.z + cB.y*v11.z
                + cA.z*v20.z + cB.z*v21.z + cA.w*v30.z + cB.w*v31.z;
        }
    }
#pragma unroll
    for (int s = 32; s > 0; s >>= 1) {
        a0 += __shfl_down(a0, s);
        a1 += __shfl_down(a1, s);
        a2 += __shfl_down(a2, s);
    }
    if (lane == 0) {
        const float* Yn = Y + (size_t)n * YST + 256;   // dense skip (c=64)
        out[n*3+0] = (a0 + Yn[0] + cb3[0] + db3[0]) * (1.f/128.f);
        out[n*3+1] = (a1 + Yn[1] + cb3[1] + db3[1]) * (1.f/128.f);
        out[n*3+2] = (a2 + Yn[2] + cb3[2] + db3[2]) * (1.f/128.f);
    }
}

} // namespace

extern "C" void kernel_launch(void* const* d_in, const int* in_sizes, int n_in,
                              void* d_out, int out_size, void* d_ws, size_t ws_size,
                              hipStream_t stream)
{
    const float* pos       = (const float*)d_in[0];
    const float* vel       = (const float*)d_in[1];
    const float* box       = (const float*)d_in[2];
    const float* box_feats = (const float*)d_in[3];
    const float* cf_w = (const float*)d_in[4];  const float* cf_b = (const float*)d_in[5];
    const float* co_w = (const float*)d_in[6];  const float* co_b = (const float*)d_in[7];
    const float* d0_w = (const float*)d_in[8];  const float* d0_b = (const float*)d_in[9];
    const float* c1_w = (const float*)d_in[10]; const float* c1_b = (const float*)d_in[11];
    const float* d1_w = (const float*)d_in[12]; const float* d1_b = (const float*)d_in[13];
    const float* c2_w = (const float*)d_in[14]; const float* c2_b = (const float*)d_in[15];
    const float* d2_w = (const float*)d_in[16]; const float* d2_b = (const float*)d_in[17];
    const float* c3_w = (const float*)d_in[18]; const float* c3_b = (const float*)d_in[19];
    const float* d3_w = (const float*)d_in[20]; const float* d3_b = (const float*)d_in[21];

    char* wsb = (char*)d_ws;
    size_t off = 0;
    auto alloc = [&](size_t bytes) {
        void* p = wsb + off;
        off = (off + bytes + 255) & ~(size_t)255;
        return p;
    };
    // Big region time-shared:
    //   [0, 3.84 MB)  : {f_d2, b_d2} during nn2gc
    //   [4 MB, 28.6)  : G0f (layer-0 fluid G-form)   -- written by fused prep,
    //   [32 MB, 44.3) : G0b (layer-0 box G-form)        consumed by gather0
    //   whole region  : bf16 G rows for layers 1/2 (overwrites G0 afterwards)
    char*  Graw = (char*)alloc((size_t)NQ * NO * 2 + 4096);   // 50 MB
    unsigned short* G = (unsigned short*)Graw;
    float* f_d2 = (float*)Graw;
    float* b_d2 = (float*)Graw + (size_t)NQ * K;
    unsigned short* G0f = (unsigned short*)(Graw + ((size_t)4 << 20));
    unsigned short* G0b = (unsigned short*)(Graw + ((size_t)32 << 20));
    int*   f_cnt  = (int*)  alloc((size_t)NQ * 4);
    int*   f_idx  = (int*)  alloc((size_t)NQ * K * 4);
    int*   f_cell = (int*)  alloc((size_t)NQ * K * 4);
    float* f_coef = (float*)alloc((size_t)NQ * K * 8 * 4);
    int*   b_cnt  = (int*)  alloc((size_t)NQ * 4);
    int*   b_idx  = (int*)  alloc((size_t)NQ * K * 4);
    int*   b_cell = (int*)  alloc((size_t)NQ * K * 4);
    float* b_coef = (float*)alloc((size_t)NQ * K * 8 * 4);
    float* x1     = (float*)alloc((size_t)NQ * 96 * 4);
    float* x2     = (float*)alloc((size_t)NQ * 64 * 4);
    unsigned short* Bt1 = (unsigned short*)alloc((size_t)NO * 96 * 2);  // 0.8 MB
    unsigned short* Bt2 = (unsigned short*)alloc((size_t)NO * 64 * 2);  // 0.5 MB
    float* W3p    = (float*)alloc((size_t)64 * 195 * 4);
    float* Y      = (float*)alloc((size_t)NQ * YST * 4);   // padded 65x4
    // grid structures
    int*   gs_f   = (int*)  alloc((size_t)(NC + 1) * 4);
    int*   gs_b   = (int*)  alloc((size_t)(NC + 1) * 4);
    float* spf    = (float*)alloc((size_t)(NQ + 1) * 4 * 4);
    int*   sif    = (int*)  alloc((size_t)NQ * 4);
    float* spb    = (float*)alloc((size_t)(NB + 1) * 4 * 4);
    int*   sib    = (int*)  alloc((size_t)NB * 4);

    dim3 b256(256);
    // 1. count + scan + scatter (single block, LDS cursors)
    grid_build_kernel<<<1, 1024, 0, stream>>>(pos, box, gs_f, gs_b,
                                              spf, sif, spb, sib);
    // 2. fused: pipelined neighbor search || heavy prep (G0, Bt, W3p, dense-0)
    nn2gc_kernel<<<PREPB + (2*NQ + 3)/4, b256, 0, stream>>>(
        pos, spf, sif, gs_f, spb, sib, gs_b,
        f_cnt, f_idx, f_d2, f_cell, f_coef,
        b_cnt, b_idx, b_d2, b_cell, b_coef,
        c1_w, d1_w, c2_w, d2_w, c3_w, d3_w,
        vel, box_feats, cf_w, co_w, d0_w, d0_b,
        Bt1, Bt2, G0f, G0b, W3p, x1);
    // 3. layer 0: G-form gather writes x1[:,0:64] (biases fused)
    gather0_kernel<<<NQ, b256, 0, stream>>>(sif,
        f_cnt, f_idx, f_cell, f_coef,
        b_cnt, b_idx, b_cell, b_coef,
        G0f, G0b, cf_b, co_b, x1);
    // 4. layer 1: G1 = relu(x1) x [c1;d1] (MFMA) ; x2 = gather(G1) + biases
    gemmGm_kernel<96><<<dim3((NQ+63)/64, 13), b256, 0, stream>>>(x1, Bt1, G, NQ);
    gatherG_kernel<0><<<NQ, b256, 0, stream>>>(sif, f_cnt, f_idx, f_cell, f_coef,
        G, c1_b, d1_b, nullptr, x2, nullptr, nullptr);
    // 5. layer 2: G2 = relu(x2) x [c2;d2] (MFMA) ;
    //    fused: x3 = gather + biases + x2 ; Y = relu(x3) * [c3;d3]
    gemmGm_kernel<64><<<dim3((NQ+63)/64, 13), b256, 0, stream>>>(x2, Bt2, G, NQ);
    gatherG_kernel<1><<<NQ, b256, 0, stream>>>(sif, f_cnt, f_idx, f_cell, f_coef,
        G, c2_b, d2_b, x2, nullptr, W3p, Y);
    // 6. layer 3 gather (O=3, padded-Y float4 loads)
    gather3_kernel<<<NBLK8, b256, 0, stream>>>(sif, f_cnt, f_idx, f_cell, f_coef,
        Y, c3_b, d3_b, (float*)d_out);

    (void)in_sizes; (void)n_in; (void)out_size; (void)ws_size;
    (void)f_d2; (void)b_d2;
}

// Round 9
// 249.980 us; speedup vs baseline: 1.0479x; 1.0479x over previous
//
#include <hip/hip_runtime.h>
#include <math.h>

namespace {

constexpr int NQ  = 6000;   // fluid particles (queries)
constexpr int NB  = 3000;   // box particles
constexpr int K   = 80;     // neighbor cap
constexpr float RAD = 0.1125f;
constexpr float RADI = 1.0f / 0.1125f;   // reciprocal (1-ulp vs divide; << bf16 noise)
constexpr float R2  = RAD * RAD;
constexpr float EPSF = 1e-12f;

constexpr int GS  = 8;           // grid dim (cell 0.125 >= RADIUS)
constexpr int NC  = GS*GS*GS;    // 512 cells
constexpr int NO  = 65 * 64;     // G row: 64 cells + 1 dense-skip col, O=64
constexpr int NBLK = (NQ + 3) / 4;            // gather blocks (4 queries each)
constexpr int NBLK8 = ((NBLK + 7) / 8) * 8;   // padded for XCD swizzle
constexpr int PREPB = 512;       // prep blocks fused into nn2gc launch
constexpr int YST = 260;         // Y row stride: 65 cells x 4 floats (padded)

typedef __attribute__((ext_vector_type(8))) short bf16x8;
typedef __attribute__((ext_vector_type(4))) float f32x4;

__device__ __forceinline__ float sgn(float x) {
    return (x > 0.f) ? 1.f : ((x < 0.f) ? -1.f : 0.f);
}

__device__ __forceinline__ unsigned int bf16rne(float f) {
    unsigned int u = __float_as_uint(f);
    return (u + 0x7fffu + ((u >> 16) & 1u)) >> 16;   // round-to-nearest-even
}
__device__ __forceinline__ float bf16f(unsigned short u) {
    return __uint_as_float(((unsigned int)u) << 16);
}
__device__ __forceinline__ int cell_of(float x, float y, float z) {
    int cx = min(max((int)(x * (float)GS), 0), GS-1);
    int cy = min(max((int)(y * (float)GS), 0), GS-1);
    int cz = min(max((int)(z * (float)GS), 0), GS-1);
    return (cz*GS + cy)*GS + cx;
}

// ball->cube + trilinear coefs from raw delta (ddx = pj - q), store at slot.
// Runs DENSE (phase 2): all lanes active, one execution per slot.
__device__ __forceinline__ void coef_compute(
    float ddx, float ddy, float ddz, int slot,
    int* __restrict__ cells, float* __restrict__ coefs)
{
    float rx = ddx * RADI, ry = ddy * RADI, rz = ddz * RADI;
    float r2 = rx*rx + ry*ry + rz*rz;
    float w1 = 1.f - r2;
    float win = (w1 > 0.f) ? w1*w1*w1 : 0.f;   // clip((1-r2)^3, 0, 1)
    float norm = sqrtf(r2);
    float rxy2 = rx*rx + ry*ry;
    float xc, yc, zc;
    if (r2 < 1e-12f) {
        xc = yc = zc = 0.f;
    } else if (1.25f * rz * rz > rxy2) {
        float s = sqrtf(3.0f * norm / (norm + fabsf(rz) + EPSF));
        xc = s * rx; yc = s * ry; zc = sgn(rz) * norm;
    } else {
        float s = norm / sqrtf(rxy2 + EPSF);
        xc = s * rx; yc = s * ry; zc = 1.5f * rz * s;
    }
    float rxy = sqrtf(xc*xc + yc*yc);
    const float FP = (float)(4.0 / M_PI);
    float u, v;
    if (rxy < EPSF) {
        u = 0.f; v = 0.f;
    } else if (fabsf(xc) >= fabsf(yc)) {
        float sx = (fabsf(xc) < EPSF) ? EPSF : xc;
        u = sgn(xc) * rxy;
        v = u * FP * atanf(yc / sx);
    } else {
        float sy = (fabsf(yc) < EPSF) ? EPSF : yc;
        v = sgn(yc) * rxy;
        u = v * FP * atanf(xc / sy);
    }
    float gx = fminf(fmaxf((u  + 1.f) * 0.5f * 3.f, 0.f), 3.f);
    float gy = fminf(fmaxf((v  + 1.f) * 0.5f * 3.f, 0.f), 3.f);
    float gz = fminf(fmaxf((zc + 1.f) * 0.5f * 3.f, 0.f), 3.f);
    int ix = min((int)floorf(gx), 2);
    int iy = min((int)floorf(gy), 2);
    int iz = min((int)floorf(gz), 2);
    float tx = gx - (float)ix, ty = gy - (float)iy, tz = gz - (float)iz;
    cells[slot] = iz*16 + iy*4 + ix;
    float wx0 = 1.f - tx, wy0 = 1.f - ty, wz0 = 1.f - tz;
    // c = dx*4 + dy*2 + dz (python loop order)
    float4 lo, hi;
    lo.x = wx0 * wy0 * wz0 * win;   // c0: (0,0,0)
    lo.y = wx0 * wy0 * tz  * win;   // c1: (0,0,1)
    lo.z = wx0 * ty  * wz0 * win;   // c2: (0,1,0)
    lo.w = wx0 * ty  * tz  * win;   // c3: (0,1,1)
    hi.x = tx  * wy0 * wz0 * win;   // c4: (1,0,0)
    hi.y = tx  * wy0 * tz  * win;   // c5: (1,0,1)
    hi.z = tx  * ty  * wz0 * win;   // c6: (1,1,0)
    hi.w = tx  * ty  * tz  * win;   // c7: (1,1,1)
    float4* cf = (float4*)(coefs + (size_t)slot * 8);
    cf[0] = lo; cf[1] = hi;
}

// ---- grid build: count (LDS atomics) + both scans, ONE single-block kernel --
__global__ __launch_bounds__(1024) void grid_build_kernel(
    const float* __restrict__ pos, const float* __restrict__ box,
    int* __restrict__ gs_f, int* __restrict__ gs_b,
    int* __restrict__ cur_f, int* __restrict__ cur_b)
{
    __shared__ int cntF[NC], cntB[NC];
    __shared__ int tmpF[NC], tmpB[NC];
    int tid = threadIdx.x;
    int half = tid >> 9, t = tid & 511;
    if (half == 0) cntF[t] = 0; else cntB[t] = 0;
    __syncthreads();
    for (int i = tid; i < NQ + NB; i += 1024) {
        if (i < NQ) {
            atomicAdd(&cntF[cell_of(pos[i*3], pos[i*3+1], pos[i*3+2])], 1);
        } else {
            int b = i - NQ;
            atomicAdd(&cntB[cell_of(box[b*3], box[b*3+1], box[b*3+2])], 1);
        }
    }
    __syncthreads();
    // parallel Hillis-Steele scans: threads 0-511 fluid, 512-1023 box
    int* cnt = half ? cntB : cntF;
    int* tmp = half ? tmpB : tmpF;
    int cv = cnt[t];
    tmp[t] = cv;
    __syncthreads();
    for (int off = 1; off < NC; off <<= 1) {
        int v = (t >= off) ? tmp[t - off] : 0;
        __syncthreads();
        tmp[t] += v;
        __syncthreads();
    }
    int* gsd = half ? gs_b : gs_f;
    int* cur = half ? cur_b : cur_f;
    int excl = tmp[t] - cv;
    gsd[t] = excl;
    cur[t] = excl;
    if (t == NC - 1) gsd[NC] = tmp[t];
}

// sorted points stored as float4 (pad) -> one dwordx4 load per candidate
__global__ __launch_bounds__(256) void scatter_pts_kernel(
    const float* __restrict__ pos, const float* __restrict__ box,
    int* __restrict__ cur_f, int* __restrict__ cur_b,
    float* __restrict__ spf, int* __restrict__ sif,
    float* __restrict__ spb, int* __restrict__ sib)
{
    int t = blockIdx.x * blockDim.x + threadIdx.x;
    if (t < NQ) {
        float x = pos[t*3], y = pos[t*3+1], z = pos[t*3+2];
        int dst = atomicAdd(&cur_f[cell_of(x,y,z)], 1);
        *reinterpret_cast<float4*>(spf + (size_t)dst*4) = make_float4(x, y, z, 0.f);
        sif[dst] = t;
    } else if (t < NQ + NB) {
        int b = t - NQ;
        float x = box[b*3], y = box[b*3+1], z = box[b*3+2];
        int dst = atomicAdd(&cur_b[cell_of(x,y,z)], 1);
        *reinterpret_cast<float4*>(spb + (size_t)dst*4) = make_float4(x, y, z, 0.f);
        sib[dst] = b;
    }
}

// -------- fused: [blocks 0..PREPB) heavy prep  |  [PREPB..) neighbor search --
// Search is pipelined: all 9 row spans loaded up front, segment-0 candidates of
// ALL rows preloaded into registers (independent loads issue together), then
// the 9 ballot/compaction steps consume registers -> one exposed load latency
// instead of nine. Rows >64 candidates take the rare tail loop. Coefs computed
// densely in phase 2.
__global__ __launch_bounds__(256) void nn2gc_kernel(
    const float* __restrict__ pos,
    const float* __restrict__ spf, const int* __restrict__ sif, const int* __restrict__ gsf,
    const float* __restrict__ spb, const int* __restrict__ sib, const int* __restrict__ gsb,
    int* __restrict__ f_cnt, int* __restrict__ f_idx, float* __restrict__ f_d2,
    int* __restrict__ f_cell, float* __restrict__ f_coef,
    int* __restrict__ b_cnt, int* __restrict__ b_idx, float* __restrict__ b_d2,
    int* __restrict__ b_cell, float* __restrict__ b_coef,
    // prep args:
    const float* __restrict__ c1w, const float* __restrict__ d1w,
    const float* __restrict__ c2w, const float* __restrict__ d2w,
    const float* __restrict__ c3w, const float* __restrict__ d3w,
    const float* __restrict__ vel, const float* __restrict__ bfeat,
    const float* __restrict__ cfw, const float* __restrict__ cow,
    const float* __restrict__ d0w, const float* __restrict__ d0b,
    unsigned short* __restrict__ Bt1, unsigned short* __restrict__ Bt2,
    unsigned short* __restrict__ G0f, unsigned short* __restrict__ G0b,
    float* __restrict__ W3p, float* __restrict__ x1)
{
    if (blockIdx.x < PREPB) {
        int stride = PREPB * 256;
        int gid = blockIdx.x * 256 + threadIdx.x;
        // G0f[j, c*32+o] = [1,vel_j] . cf_w[c,:,o]   (bf16, 2 o's per iter)
        for (int i = gid; i < NQ * 1024; i += stride) {
            int j = i >> 10, rr = i & 1023, c = rr >> 4, op = (rr & 15) * 2;
            float vx = vel[j*3+0], vy = vel[j*3+1], vz = vel[j*3+2];
            const float* w = cfw + (size_t)c * 128;    // cf_w[c][f][o], f-stride 32
            float s0 = w[op]   + vx*w[32+op]   + vy*w[64+op]   + vz*w[96+op];
            float s1 = w[op+1] + vx*w[32+op+1] + vy*w[64+op+1] + vz*w[96+op+1];
            *reinterpret_cast<unsigned int*>(G0f + (size_t)j * 2048 + c*32 + op) =
                bf16rne(s0) | (bf16rne(s1) << 16);
        }
        // G0b[j, c*32+o] = bfeat_j . co_w[c,:,o]
        for (int i = gid; i < NB * 1024; i += stride) {
            int j = i >> 10, rr = i & 1023, c = rr >> 4, op = (rr & 15) * 2;
            float b0 = bfeat[j*3+0], b1 = bfeat[j*3+1], b2 = bfeat[j*3+2];
            const float* w = cow + (size_t)c * 96;     // co_w[c][f][o], f-stride 32
            float s0 = b0*w[op]   + b1*w[32+op]   + b2*w[64+op];
            float s1 = b0*w[op+1] + b1*w[32+op+1] + b2*w[64+op+1];
            *reinterpret_cast<unsigned int*>(G0b + (size_t)j * 2048 + c*32 + op) =
                bf16rne(s0) | (bf16rne(s1) << 16);
        }
        for (int i = gid; i < NO * 96; i += stride) {   // Bt1[n,f]; n = c*64+o
            int n = i / 96, f = i % 96, c = n >> 6, o = n & 63;
            float v = (c < 64) ? c1w[((size_t)c*96 + f)*64 + o] : d1w[f*64 + o];
            Bt1[i] = (unsigned short)bf16rne(v);
        }
        for (int i = gid; i < NO * 64; i += stride) {
            int n = i / 64, f = i % 64, c = n >> 6, o = n & 63;
            float v = (c < 64) ? c2w[((size_t)c*64 + f)*64 + o] : d2w[f*64 + o];
            Bt2[i] = (unsigned short)bf16rne(v);
        }
        for (int i = gid; i < 64 * 195; i += stride) {   // W3p[f][c*3+o]
            int f = i / 195, r = i % 195, c = r / 3, o = r % 3;
            W3p[i] = (c < 64) ? c3w[(c*64 + f)*3 + o] : d3w[f*3 + o];
        }
        for (int i = gid; i < NQ * 32; i += stride) {    // dense-0 -> x1[:,64:96]
            int n = i >> 5, o = i & 31;
            float acc = d0b[o] + d0w[o]
                      + vel[n*3+0] * d0w[32 + o]
                      + vel[n*3+1] * d0w[64 + o]
                      + vel[n*3+2] * d0w[96 + o];
            x1[n*96 + 64 + o] = acc;
        }
        return;
    }
    int gw = (int)(blockIdx.x - PREPB) * 4 + ((int)threadIdx.x >> 6);
    int lane = threadIdx.x & 63;
    if (gw >= 2 * NQ) return;
    bool isF = gw < NQ;
    int wid = isF ? gw : gw - NQ;
    const float* sp = isF ? spf : spb;
    const int*   si = isF ? sif : sib;
    const int*   gs = isF ? gsf : gsb;
    int*   cnt   = isF ? f_cnt  : b_cnt;
    int*   idxs  = isF ? f_idx  : b_idx;
    float* d2s   = isF ? f_d2   : b_d2;
    int*   cells = isF ? f_cell : b_cell;
    float* coefs = isF ? f_coef : b_coef;
    int    tot   = isF ? NQ : NB;
    float qx = pos[wid*3+0], qy = pos[wid*3+1], qz = pos[wid*3+2];
    int cx = min(max((int)(qx * (float)GS), 0), GS-1);
    int cy = min(max((int)(qy * (float)GS), 0), GS-1);
    int cz = min(max((int)(qz * (float)GS), 0), GS-1);
    int x0 = max(cx-1, 0), x1c = min(cx+1, GS-1);
    int base = wid * K;
    int c = 0;

    auto process = [&](bool hit, int oj, float ddx, float ddy, float ddz, float d2) {
        unsigned long long m = __ballot(hit);
        int pc = __popcll(m);
        if (pc == 0) return;
        if (c + pc <= K) {
            if (hit) {
                int p = c + __popcll(m & ((1ull << lane) - 1ull));
                idxs[base + p] = oj;
                d2s [base + p] = d2;
                float* cf = coefs + (size_t)(base + p) * 8;
                cf[0] = ddx; cf[1] = ddy; cf[2] = ddz;   // deltas; coefs in phase 2
            }
            c += pc;
        } else {
            // rare overflow: keep the K nearest (top_k semantics)
            while (m) {
                int l = __ffsll((unsigned long long)m) - 1;
                m &= m - 1ull;
                float dd = __shfl(d2, l);
                int jv = __shfl(oj, l);
                float ax = __shfl(ddx, l), ay = __shfl(ddy, l), az = __shfl(ddz, l);
                int slot = -1;
                if (c < K) { slot = c; c++; }
                else {
                    float mx = -1.f; int am = 0;
                    for (int s = 0; s < K; ++s) {
                        float v = d2s[base + s];
                        if (v > mx) { mx = v; am = s; }
                    }
                    if (dd < mx) slot = am;
                }
                if (slot >= 0 && lane == 0) {
                    idxs[base + slot] = jv;
                    d2s [base + slot] = dd;
                    float* cf = coefs + (size_t)(base + slot) * 8;
                    cf[0] = ax; cf[1] = ay; cf[2] = az;
                }
            }
        }
    };

    // spans of all 9 (z,y) rows -- wave-uniform loads, issued together
    int s0v[9], s1v[9];
#pragma unroll
    for (int r = 0; r < 9; ++r) {
        int z = cz + (r / 3) - 1, y = cy + (r % 3) - 1;
        bool ok = ((unsigned)z < (unsigned)GS) && ((unsigned)y < (unsigned)GS);
        int row = ok ? (z*GS + y)*GS : 0;
        int a0 = gs[row + x0];
        int a1 = gs[row + x1c + 1];
        s0v[r] = a0;
        s1v[r] = ok ? a1 : a0;
    }
    // preload segment-0 candidate of every row (independent -> all in flight)
    int    ojv[9];
    float4 pv [9];
#pragma unroll
    for (int r = 0; r < 9; ++r) {
        int a = min(s0v[r] + lane, tot - 1);
        ojv[r] = si[a];
        pv [r] = *reinterpret_cast<const float4*>(sp + (size_t)a * 4);
    }
    // process the 9 rows from registers
#pragma unroll
    for (int r = 0; r < 9; ++r) {
        int ii = s0v[r] + lane;
        float ddx = pv[r].x - qx, ddy = pv[r].y - qy, ddz = pv[r].z - qz;
        float d2 = ddx*ddx + ddy*ddy + ddz*ddz;
        int oj = ojv[r];
        bool hit = (ii < s1v[r]) && (d2 <= R2) && !(isF && oj == wid);
        process(hit, oj, ddx, ddy, ddz, d2);
    }
    // rare tails: rows with more than 64 candidates
#pragma unroll
    for (int r = 0; r < 9; ++r) {
        for (int j0 = s0v[r] + 64; j0 < s1v[r]; j0 += 64) {
            int ii = j0 + lane;
            int a = min(ii, tot - 1);
            int oj = si[a];
            float4 p = *reinterpret_cast<const float4*>(sp + (size_t)a * 4);
            float ddx = p.x - qx, ddy = p.y - qy, ddz = p.z - qz;
            float d2 = ddx*ddx + ddy*ddy + ddz*ddz;
            bool hit = (ii < s1v[r]) && (d2 <= R2) && !(isF && oj == wid);
            process(hit, oj, ddx, ddy, ddz, d2);
        }
    }
    // phase 2: dense coef computation (one pass, all lanes active)
    for (int k2 = lane; k2 < c; k2 += 64) {
        const float4 d = *reinterpret_cast<const float4*>(coefs + (size_t)(base + k2) * 8);
        coef_compute(d.x, d.y, d.z, base + k2, cells, coefs);
    }
    if (lane == 0) cnt[wid] = c;
}

// ---- layer-0 gather (G-form): one block per query, 4 waves, two 32-lane
//      halves process 2 neighbors/iter. jcb = j*2048 + cell*32 precomputed. ---
__global__ __launch_bounds__(256) void gather0_kernel(
    const int* __restrict__ order,
    const int* __restrict__ f_cnt, const int* __restrict__ f_idx,
    const int* __restrict__ f_cell, const float* __restrict__ f_coef,
    const int* __restrict__ b_cnt, const int* __restrict__ b_idx,
    const int* __restrict__ b_cell, const float* __restrict__ b_coef,
    const unsigned short* __restrict__ G0f, const unsigned short* __restrict__ G0b,
    const float* __restrict__ cfb, const float* __restrict__ cob,
    float* __restrict__ x1)
{
    __shared__ __align__(16) float coefF[K * 8];
    __shared__ __align__(16) float coefB[K * 8];
    __shared__ int jF[K], jB[K];
    __shared__ float partF[8][32], partB[8][32];
    int lb = (blockIdx.x & 7) * (gridDim.x >> 3) + (blockIdx.x >> 3);  // XCD swizzle
    int tid = threadIdx.x;
    int wv = tid >> 6, lane = tid & 63;
    int h = lane >> 5, o = lane & 31;
    int r = wv * 2 + h;
    int n = order[lb];
    int cnf = f_cnt[n], cnb = b_cnt[n];
    {
        const float4* srcF = (const float4*)(f_coef + (size_t)n * K * 8);
        const float4* srcB = (const float4*)(b_coef + (size_t)n * K * 8);
        for (int i = tid; i < cnf * 2; i += 256) ((float4*)coefF)[i] = srcF[i];
        for (int i = tid; i < cnb * 2; i += 256) ((float4*)coefB)[i] = srcB[i];
        for (int i = tid; i < cnf; i += 256) jF[i] = f_idx[n*K + i] * 2048 + f_cell[n*K + i] * 32;
        for (int i = tid; i < cnb; i += 256) jB[i] = b_idx[n*K + i] * 2048 + b_cell[n*K + i] * 32;
    }
    __syncthreads();
    // c = dx*4+dy*2+dz ; cell = cbse + dz*16 + dy*4 + dx
    float af = 0.f;
#pragma unroll 2
    for (int k = r; k < cnf; k += 8) {
        const unsigned short* Gj = G0f + jF[k] + o;
        float4 cA = *reinterpret_cast<const float4*>(coefF + k*8);
        float4 cB = *reinterpret_cast<const float4*>(coefF + k*8 + 4);
        af += cA.x * bf16f(Gj[ 0 * 32]);
        af += cA.y * bf16f(Gj[16 * 32]);
        af += cA.z * bf16f(Gj[ 4 * 32]);
        af += cA.w * bf16f(Gj[20 * 32]);
        af += cB.x * bf16f(Gj[ 1 * 32]);
        af += cB.y * bf16f(Gj[17 * 32]);
        af += cB.z * bf16f(Gj[ 5 * 32]);
        af += cB.w * bf16f(Gj[21 * 32]);
    }
    float ab = 0.f;
#pragma unroll 2
    for (int k = r; k < cnb; k += 8) {
        const unsigned short* Gj = G0b + jB[k] + o;
        float4 cA = *reinterpret_cast<const float4*>(coefB + k*8);
        float4 cB = *reinterpret_cast<const float4*>(coefB + k*8 + 4);
        ab += cA.x * bf16f(Gj[ 0 * 32]);
        ab += cA.y * bf16f(Gj[16 * 32]);
        ab += cA.z * bf16f(Gj[ 4 * 32]);
        ab += cA.w * bf16f(Gj[20 * 32]);
        ab += cB.x * bf16f(Gj[ 1 * 32]);
        ab += cB.y * bf16f(Gj[17 * 32]);
        ab += cB.z * bf16f(Gj[ 5 * 32]);
        ab += cB.w * bf16f(Gj[21 * 32]);
    }
    partF[r][o] = af;
    partB[r][o] = ab;
    __syncthreads();
    if (tid < 64) {
        int oo = tid & 31;
        if (tid < 32) {
            float s = cfb[oo];
#pragma unroll
            for (int q = 0; q < 8; ++q) s += partF[q][oo];
            x1[(size_t)n * 96 + 32 + oo] = s;      // a_cf -> x1[:,32:64]
        } else {
            float s = cob[oo];
#pragma unroll
            for (int q = 0; q < 8; ++q) s += partB[q][oo];
            x1[(size_t)n * 96 + oo] = s;           // a_co -> x1[:,0:32]
        }
    }
}

// ---- MFMA G-GEMM: G[j, n] = relu(feats[j,:]) . Bt[n,:]  (bf16 in/out) -------
// A-tile staged ONCE per block; loops over NT n-tiles (65 = 13*5).
// (round-6 direct-store epilogue: LDS C-tile variant regressed in R8)
template<int F>
__global__ __launch_bounds__(256) void gemmGm_kernel(
    const float* __restrict__ feats,            // [M,F] fp32
    const unsigned short* __restrict__ Bt,      // [NO,F] bf16 (n-major)
    unsigned short* __restrict__ G,             // [M,NO] bf16
    int M)
{
    constexpr int NT = 5;
    constexpr int AST = F + 8;
    __shared__ unsigned short As[64 * AST];     // [m][k]
    __shared__ unsigned short Bs[64 * AST];     // [n][k]
    int tid = threadIdx.x, lane = tid & 63, wv = tid >> 6;
    int m0 = blockIdx.x * 64;
    int nt0 = blockIdx.y * NT;
    for (int i = tid; i < 64 * F / 4; i += 256) {
        int m = i / (F / 4), k4 = i % (F / 4);
        int gm = m0 + m; if (gm >= M) gm = M - 1;
        float4 av = *reinterpret_cast<const float4*>(feats + (size_t)gm * F + k4 * 4);
        uint2 ov;
        ov.x = bf16rne(fmaxf(av.x, 0.f)) | (bf16rne(fmaxf(av.y, 0.f)) << 16);
        ov.y = bf16rne(fmaxf(av.z, 0.f)) | (bf16rne(fmaxf(av.w, 0.f)) << 16);
        *reinterpret_cast<uint2*>(As + m * AST + k4 * 4) = ov;
    }
    int mr = lane & 15, quad = lane >> 4;
    for (int t = 0; t < NT; ++t) {
        int no0 = (nt0 + t) * 64;
        __syncthreads();   // waves done reading Bs (t=0: harmless)
        for (int i = tid; i < 64 * F / 8; i += 256) {
            int nn = i / (F / 8), k8 = i % (F / 8);
            *reinterpret_cast<uint4*>(Bs + nn * AST + k8 * 8) =
                *reinterpret_cast<const uint4*>(Bt + (size_t)(no0 + nn) * F + k8 * 8);
        }
        __syncthreads();   // Bs (and As on t=0) visible
        f32x4 acc[4] = {{0.f,0.f,0.f,0.f},{0.f,0.f,0.f,0.f},
                        {0.f,0.f,0.f,0.f},{0.f,0.f,0.f,0.f}};
#pragma unroll
        for (int kc = 0; kc < F; kc += 32) {
            bf16x8 a = *reinterpret_cast<const bf16x8*>(As + (wv*16 + mr) * AST + kc + quad*8);
#pragma unroll
            for (int q = 0; q < 4; ++q) {
                bf16x8 b = *reinterpret_cast<const bf16x8*>(Bs + (q*16 + mr) * AST + kc + quad*8);
                acc[q] = __builtin_amdgcn_mfma_f32_16x16x32_bf16(a, b, acc[q], 0, 0, 0);
            }
        }
        // C layout: col = lane&15, row = quad*4 + reg
#pragma unroll
        for (int q = 0; q < 4; ++q) {
#pragma unroll
            for (int rr = 0; rr < 4; ++rr) {
                int gm = m0 + wv*16 + quad*4 + rr;
                if (gm < M)
                    G[(size_t)gm * NO + no0 + q*16 + mr] = (unsigned short)bf16rne(acc[q][rr]);
            }
        }
    }
}

// ---- G-gather v2: ONE QUERY PER BLOCK, k-loop split across the 4 waves ------
// jcb = j*NO + cell*64 precomputed in LDS (shorter dependent address chain).
// FUSEY=1 additionally fuses Y = relu(x3) * W3p using all 256 threads
// (Y rows padded: 65 cells x 4 floats, stride YST).
template<int FUSEY>
__global__ __launch_bounds__(256) void gatherG_kernel(
    const int* __restrict__ order,
    const int* __restrict__ cnt, const int* __restrict__ nidx,
    const int* __restrict__ ncell, const float* __restrict__ ncoef,
    const unsigned short* __restrict__ G,
    const float* __restrict__ cb, const float* __restrict__ db,
    const float* __restrict__ resid, float* __restrict__ out,
    const float* __restrict__ W3p, float* __restrict__ Y)
{
    __shared__ __align__(16) float coefL[K * 8];   // 2.5 KB
    __shared__ int jL[K];
    __shared__ float part[3][64];
    __shared__ float xs[64];
    int lb = (blockIdx.x & 7) * (gridDim.x >> 3) + (blockIdx.x >> 3);  // XCD swizzle
    int tid = threadIdx.x;
    int wv = tid >> 6, lane = tid & 63;
    int n = order[lb];
    int cn = cnt[n];
    // cooperative staging: coefs (float4 x 2 per k), combined j*NO+cell*64
    {
        const float4* src = (const float4*)(ncoef + (size_t)n * K * 8);
        float4* dst = (float4*)coefL;
        for (int i = tid; i < cn * 2; i += 256) dst[i] = src[i];
        for (int i = tid; i < cn; i += 256)
            jL[i] = nidx[n*K + i] * NO + ncell[n*K + i] * 64;
    }
    __syncthreads();
    float a0 = 0.f, a1 = 0.f, a2 = 0.f, a3 = 0.f;
#pragma unroll 2
    for (int k = wv; k < cn; k += 4) {
        float4 cA = *reinterpret_cast<const float4*>(coefL + k*8);      // c=0..3 (dx=0)
        float4 cB = *reinterpret_cast<const float4*>(coefL + k*8 + 4);  // c=4..7 (dx=1)
        const unsigned short* Gj = G + jL[k] + lane;
        // c = dx*4+dy*2+dz ; cell = cbse + dz*16 + dy*4 + dx
        a0 += cA.x * bf16f(Gj[ 0 * 64]);
        a1 += cA.y * bf16f(Gj[16 * 64]);
        a2 += cA.z * bf16f(Gj[ 4 * 64]);
        a3 += cA.w * bf16f(Gj[20 * 64]);
        a0 += cB.x * bf16f(Gj[ 1 * 64]);
        a1 += cB.y * bf16f(Gj[17 * 64]);
        a2 += cB.z * bf16f(Gj[ 5 * 64]);
        a3 += cB.w * bf16f(Gj[21 * 64]);
    }
    float s = (a0 + a1) + (a2 + a3);
    if (wv > 0) part[wv - 1][lane] = s;
    __syncthreads();
    if (wv == 0) {
        float acc = cb[lane] + db[lane] + s
                  + part[0][lane] + part[1][lane] + part[2][lane];
        acc += bf16f(G[(size_t)n * NO + 64*64 + lane]);   // dense skip
        if (resid) acc += resid[(size_t)n * 64 + lane];
        if (!FUSEY) {
            out[(size_t)n * 64 + lane] = acc;
        } else {
            xs[lane] = fmaxf(acc, 0.f);
        }
    }
    if (FUSEY) {
        __syncthreads();
        // fused y3t: Y[n, c*4+o] = sum_f relu(x3[n,f]) * W3p[f, c*3+o]  (o<3)
        for (int idx = tid; idx < YST; idx += 256) {
            int cc = idx >> 2, o = idx & 3;
            if (o < 3) {
                float sum = 0.f;
#pragma unroll 16
                for (int f = 0; f < 64; ++f) sum += xs[f] * W3p[f*195 + cc*3 + o];
                Y[(size_t)n * YST + idx] = sum;
            }
        }
    }
}

// ---- layer-3 gather: lane = neighbor; corners load as aligned float4 pairs --
__global__ __launch_bounds__(256) void gather3_kernel(
    const int* __restrict__ order,
    const int* __restrict__ cnt, const int* __restrict__ nidx,
    const int* __restrict__ ncell, const float* __restrict__ ncoef,
    const float* __restrict__ Y,
    const float* __restrict__ cb3, const float* __restrict__ db3,
    float* __restrict__ out)
{
    int lb = (blockIdx.x & 7) * (gridDim.x >> 3) + (blockIdx.x >> 3);
    int gw = lb * 4 + ((int)threadIdx.x >> 6);
    int lane = threadIdx.x & 63;
    if (gw >= NQ) return;
    int n = order[gw];
    int cn = cnt[n];
    float a0 = 0.f, a1 = 0.f, a2 = 0.f;
#pragma unroll
    for (int seg = 0; seg < 2; ++seg) {
        int kidx = seg * 64 + lane;
        if (kidx < cn) {
            int j  = nidx [n*K + kidx];
            int cb = ncell[n*K + kidx];
            const float* cf = ncoef + (size_t)(n*K + kidx) * 8;
            float4 cA = *reinterpret_cast<const float4*>(cf);      // c=0..3 (dx=0)
            float4 cB = *reinterpret_cast<const float4*>(cf + 4);  // c=4..7 (dx=1)
            const float* Yj = Y + (size_t)j * YST + (size_t)cb * 4;
            // cell offsets {0,16,4,20} <-> cA.{x,y,z,w}; +1 (dx=1) <-> cB
            float4 v00 = *reinterpret_cast<const float4*>(Yj +  0 * 4);
            float4 v01 = *reinterpret_cast<const float4*>(Yj +  1 * 4);
            float4 v10 = *reinterpret_cast<const float4*>(Yj + 16 * 4);
            float4 v11 = *reinterpret_cast<const float4*>(Yj + 17 * 4);
            float4 v20 = *reinterpret_cast<const float4*>(Yj +  4 * 4);
            float4 v21 = *reinterpret_cast<const float4*>(Yj +  5 * 4);
            float4 v30 = *reinterpret_cast<const float4*>(Yj + 20 * 4);
            float4 v31 = *reinterpret_cast<const float4*>(Yj + 21 * 4);
            a0 += cA.x*v00.x + cB.x*v01.x + cA.y*v10.x + cB.y*v11.x
                + cA.z*v20.x + cB.z*v21.x + cA.w*v30.x + cB.w*v31.x;
            a1 += cA.x*v00.y + cB.x*v01.y + cA.y*v10.y + cB.y*v11.y
                + cA.z*v20.y + cB.z*v21.y + cA.w*v30.y + cB.w*v31.y;
            a2 += cA.x*v00.z + cB.x*v01.z + cA.y*v10.z + cB.y*v11.z
                + cA.z*v20.z + cB.z*v21.z + cA.w*v30.z + cB.w*v31.z;
        }
    }
#pragma unroll
    for (int s = 32; s > 0; s >>= 1) {
        a0 += __shfl_down(a0, s);
        a1 += __shfl_down(a1, s);
        a2 += __shfl_down(a2, s);
    }
    if (lane == 0) {
        const float* Yn = Y + (size_t)n * YST + 256;   // dense skip (c=64)
        out[n*3+0] = (a0 + Yn[0] + cb3[0] + db3[0]) * (1.f/128.f);
        out[n*3+1] = (a1 + Yn[1] + cb3[1] + db3[1]) * (1.f/128.f);
        out[n*3+2] = (a2 + Yn[2] + cb3[2] + db3[2]) * (1.f/128.f);
    }
}

} // namespace

extern "C" void kernel_launch(void* const* d_in, const int* in_sizes, int n_in,
                              void* d_out, int out_size, void* d_ws, size_t ws_size,
                              hipStream_t stream)
{
    const float* pos       = (const float*)d_in[0];
    const float* vel       = (const float*)d_in[1];
    const float* box       = (const float*)d_in[2];
    const float* box_feats = (const float*)d_in[3];
    const float* cf_w = (const float*)d_in[4];  const float* cf_b = (const float*)d_in[5];
    const float* co_w = (const float*)d_in[6];  const float* co_b = (const float*)d_in[7];
    const float* d0_w = (const float*)d_in[8];  const float* d0_b = (const float*)d_in[9];
    const float* c1_w = (const float*)d_in[10]; const float* c1_b = (const float*)d_in[11];
    const float* d1_w = (const float*)d_in[12]; const float* d1_b = (const float*)d_in[13];
    const float* c2_w = (const float*)d_in[14]; const float* c2_b = (const float*)d_in[15];
    const float* d2_w = (const float*)d_in[16]; const float* d2_b = (const float*)d_in[17];
    const float* c3_w = (const float*)d_in[18]; const float* c3_b = (const float*)d_in[19];
    const float* d3_w = (const float*)d_in[20]; const float* d3_b = (const float*)d_in[21];

    char* wsb = (char*)d_ws;
    size_t off = 0;
    auto alloc = [&](size_t bytes) {
        void* p = wsb + off;
        off = (off + bytes + 255) & ~(size_t)255;
        return p;
    };
    // Big region time-shared:
    //   [0, 3.84 MB)  : {f_d2, b_d2} during nn2gc
    //   [4 MB, 28.6)  : G0f (layer-0 fluid G-form)   -- written by fused prep,
    //   [32 MB, 44.3) : G0b (layer-0 box G-form)        consumed by gather0
    //   whole region  : bf16 G rows for layers 1/2 (overwrites G0 afterwards)
    char*  Graw = (char*)alloc((size_t)NQ * NO * 2 + 4096);   // 50 MB
    unsigned short* G = (unsigned short*)Graw;
    float* f_d2 = (float*)Graw;
    float* b_d2 = (float*)Graw + (size_t)NQ * K;
    unsigned short* G0f = (unsigned short*)(Graw + ((size_t)4 << 20));
    unsigned short* G0b = (unsigned short*)(Graw + ((size_t)32 << 20));
    int*   f_cnt  = (int*)  alloc((size_t)NQ * 4);
    int*   f_idx  = (int*)  alloc((size_t)NQ * K * 4);
    int*   f_cell = (int*)  alloc((size_t)NQ * K * 4);
    float* f_coef = (float*)alloc((size_t)NQ * K * 8 * 4);
    int*   b_cnt  = (int*)  alloc((size_t)NQ * 4);
    int*   b_idx  = (int*)  alloc((size_t)NQ * K * 4);
    int*   b_cell = (int*)  alloc((size_t)NQ * K * 4);
    float* b_coef = (float*)alloc((size_t)NQ * K * 8 * 4);
    float* x1     = (float*)alloc((size_t)NQ * 96 * 4);
    float* x2     = (float*)alloc((size_t)NQ * 64 * 4);
    unsigned short* Bt1 = (unsigned short*)alloc((size_t)NO * 96 * 2);  // 0.8 MB
    unsigned short* Bt2 = (unsigned short*)alloc((size_t)NO * 64 * 2);  // 0.5 MB
    float* W3p    = (float*)alloc((size_t)64 * 195 * 4);
    float* Y      = (float*)alloc((size_t)NQ * YST * 4);   // padded 65x4
    // grid structures
    int*   gs_f   = (int*)  alloc((size_t)(NC + 1) * 4);
    int*   gs_b   = (int*)  alloc((size_t)(NC + 1) * 4);
    int*   cur_f  = (int*)  alloc((size_t)NC * 4);
    int*   cur_b  = (int*)  alloc((size_t)NC * 4);
    float* spf    = (float*)alloc((size_t)(NQ + 1) * 4 * 4);
    int*   sif    = (int*)  alloc((size_t)NQ * 4);
    float* spb    = (float*)alloc((size_t)(NB + 1) * 4 * 4);
    int*   sib    = (int*)  alloc((size_t)NB * 4);

    dim3 b256(256);
    // 1. count + scan (single block, LDS-only)
    grid_build_kernel<<<1, 1024, 0, stream>>>(pos, box, gs_f, gs_b, cur_f, cur_b);
    // 2. reorder points into cell-sorted arrays (float4-padded)
    scatter_pts_kernel<<<(NQ + NB + 255)/256, b256, 0, stream>>>(
        pos, box, cur_f, cur_b, spf, sif, spb, sib);
    // 3. fused: pipelined neighbor search || heavy prep (G0, Bt, W3p, dense-0)
    nn2gc_kernel<<<PREPB + (2*NQ + 3)/4, b256, 0, stream>>>(
        pos, spf, sif, gs_f, spb, sib, gs_b,
        f_cnt, f_idx, f_d2, f_cell, f_coef,
        b_cnt, b_idx, b_d2, b_cell, b_coef,
        c1_w, d1_w, c2_w, d2_w, c3_w, d3_w,
        vel, box_feats, cf_w, co_w, d0_w, d0_b,
        Bt1, Bt2, G0f, G0b, W3p, x1);
    // 4. layer 0: G-form gather writes x1[:,0:64] (biases fused)
    gather0_kernel<<<NQ, b256, 0, stream>>>(sif,
        f_cnt, f_idx, f_cell, f_coef,
        b_cnt, b_idx, b_cell, b_coef,
        G0f, G0b, cf_b, co_b, x1);
    // 5. layer 1: G1 = relu(x1) x [c1;d1] (MFMA) ; x2 = gather(G1) + biases
    gemmGm_kernel<96><<<dim3((NQ+63)/64, 13), b256, 0, stream>>>(x1, Bt1, G, NQ);
    gatherG_kernel<0><<<NQ, b256, 0, stream>>>(sif, f_cnt, f_idx, f_cell, f_coef,
        G, c1_b, d1_b, nullptr, x2, nullptr, nullptr);
    // 6. layer 2: G2 = relu(x2) x [c2;d2] (MFMA) ;
    //    fused: x3 = gather + biases + x2 ; Y = relu(x3) * [c3;d3]
    gemmGm_kernel<64><<<dim3((NQ+63)/64, 13), b256, 0, stream>>>(x2, Bt2, G, NQ);
    gatherG_kernel<1><<<NQ, b256, 0, stream>>>(sif, f_cnt, f_idx, f_cell, f_coef,
        G, c2_b, d2_b, x2, nullptr, W3p, Y);
    // 7. layer 3 gather (O=3, padded-Y float4 loads)
    gather3_kernel<<<NBLK8, b256, 0, stream>>>(sif, f_cnt, f_idx, f_cell, f_coef,
        Y, c3_b, d3_b, (float*)d_out);

    (void)in_sizes; (void)n_in; (void)out_size; (void)ws_size;
    (void)f_d2; (void)b_d2;
}

// Round 10
// 240.707 us; speedup vs baseline: 1.0882x; 1.0385x over previous
//
#include <hip/hip_runtime.h>
#include <math.h>

namespace {

constexpr int NQ  = 6000;   // fluid particles (queries)
constexpr int NB  = 3000;   // box particles
constexpr int K   = 80;     // neighbor cap
constexpr float RAD = 0.1125f;
constexpr float RADI = 1.0f / 0.1125f;   // reciprocal (1-ulp vs divide; << bf16 noise)
constexpr float R2  = RAD * RAD;
constexpr float EPSF = 1e-12f;

constexpr int GS  = 8;           // grid dim (cell 0.125 >= RADIUS)
constexpr int NC  = GS*GS*GS;    // 512 cells
constexpr int NO  = 65 * 64;     // G row: 64 cells + 1 dense-skip col, O=64
constexpr int NBLK = (NQ + 3) / 4;            // gather blocks (4 queries each)
constexpr int NBLK8 = ((NBLK + 7) / 8) * 8;   // padded for XCD swizzle
constexpr int PREPB = 512;       // prep blocks fused into nn2gc launch

typedef __attribute__((ext_vector_type(8))) short bf16x8;
typedef __attribute__((ext_vector_type(4))) float f32x4;

__device__ __forceinline__ float sgn(float x) {
    return (x > 0.f) ? 1.f : ((x < 0.f) ? -1.f : 0.f);
}

__device__ __forceinline__ unsigned int bf16rne(float f) {
    unsigned int u = __float_as_uint(f);
    return (u + 0x7fffu + ((u >> 16) & 1u)) >> 16;   // round-to-nearest-even
}
__device__ __forceinline__ float bf16f(unsigned short u) {
    return __uint_as_float(((unsigned int)u) << 16);
}
__device__ __forceinline__ int cell_of(float x, float y, float z) {
    int cx = min(max((int)(x * (float)GS), 0), GS-1);
    int cy = min(max((int)(y * (float)GS), 0), GS-1);
    int cz = min(max((int)(z * (float)GS), 0), GS-1);
    return (cz*GS + cy)*GS + cx;
}

// ball->cube + trilinear coefs from raw delta (ddx = pj - q), store at slot.
// Runs DENSE (phase 2): all lanes active, one execution per slot.
__device__ __forceinline__ void coef_compute(
    float ddx, float ddy, float ddz, int slot,
    int* __restrict__ cells, float* __restrict__ coefs)
{
    float rx = ddx * RADI, ry = ddy * RADI, rz = ddz * RADI;
    float r2 = rx*rx + ry*ry + rz*rz;
    float w1 = 1.f - r2;
    float win = (w1 > 0.f) ? w1*w1*w1 : 0.f;   // clip((1-r2)^3, 0, 1)
    float norm = sqrtf(r2);
    float rxy2 = rx*rx + ry*ry;
    float xc, yc, zc;
    if (r2 < 1e-12f) {
        xc = yc = zc = 0.f;
    } else if (1.25f * rz * rz > rxy2) {
        float s = sqrtf(3.0f * norm / (norm + fabsf(rz) + EPSF));
        xc = s * rx; yc = s * ry; zc = sgn(rz) * norm;
    } else {
        float s = norm / sqrtf(rxy2 + EPSF);
        xc = s * rx; yc = s * ry; zc = 1.5f * rz * s;
    }
    float rxy = sqrtf(xc*xc + yc*yc);
    const float FP = (float)(4.0 / M_PI);
    float u, v;
    if (rxy < EPSF) {
        u = 0.f; v = 0.f;
    } else if (fabsf(xc) >= fabsf(yc)) {
        float sx = (fabsf(xc) < EPSF) ? EPSF : xc;
        u = sgn(xc) * rxy;
        v = u * FP * atanf(yc / sx);
    } else {
        float sy = (fabsf(yc) < EPSF) ? EPSF : yc;
        v = sgn(yc) * rxy;
        u = v * FP * atanf(xc / sy);
    }
    float gx = fminf(fmaxf((u  + 1.f) * 0.5f * 3.f, 0.f), 3.f);
    float gy = fminf(fmaxf((v  + 1.f) * 0.5f * 3.f, 0.f), 3.f);
    float gz = fminf(fmaxf((zc + 1.f) * 0.5f * 3.f, 0.f), 3.f);
    int ix = min((int)floorf(gx), 2);
    int iy = min((int)floorf(gy), 2);
    int iz = min((int)floorf(gz), 2);
    float tx = gx - (float)ix, ty = gy - (float)iy, tz = gz - (float)iz;
    cells[slot] = iz*16 + iy*4 + ix;
    float wx0 = 1.f - tx, wy0 = 1.f - ty, wz0 = 1.f - tz;
    // c = dx*4 + dy*2 + dz (python loop order)
    float4 lo, hi;
    lo.x = wx0 * wy0 * wz0 * win;   // c0: (0,0,0)
    lo.y = wx0 * wy0 * tz  * win;   // c1: (0,0,1)
    lo.z = wx0 * ty  * wz0 * win;   // c2: (0,1,0)
    lo.w = wx0 * ty  * tz  * win;   // c3: (0,1,1)
    hi.x = tx  * wy0 * wz0 * win;   // c4: (1,0,0)
    hi.y = tx  * wy0 * tz  * win;   // c5: (1,0,1)
    hi.z = tx  * ty  * wz0 * win;   // c6: (1,1,0)
    hi.w = tx  * ty  * tz  * win;   // c7: (1,1,1)
    float4* cf = (float4*)(coefs + (size_t)slot * 8);
    cf[0] = lo; cf[1] = hi;
}

// ---- grid build: count (LDS atomics) + both scans, ONE single-block kernel --
__global__ __launch_bounds__(1024) void grid_build_kernel(
    const float* __restrict__ pos, const float* __restrict__ box,
    int* __restrict__ gs_f, int* __restrict__ gs_b,
    int* __restrict__ cur_f, int* __restrict__ cur_b)
{
    __shared__ int cntF[NC], cntB[NC];
    __shared__ int tmpF[NC], tmpB[NC];
    int tid = threadIdx.x;
    int half = tid >> 9, t = tid & 511;
    if (half == 0) cntF[t] = 0; else cntB[t] = 0;
    __syncthreads();
    for (int i = tid; i < NQ + NB; i += 1024) {
        if (i < NQ) {
            atomicAdd(&cntF[cell_of(pos[i*3], pos[i*3+1], pos[i*3+2])], 1);
        } else {
            int b = i - NQ;
            atomicAdd(&cntB[cell_of(box[b*3], box[b*3+1], box[b*3+2])], 1);
        }
    }
    __syncthreads();
    // parallel Hillis-Steele scans: threads 0-511 fluid, 512-1023 box
    int* cnt = half ? cntB : cntF;
    int* tmp = half ? tmpB : tmpF;
    int cv = cnt[t];
    tmp[t] = cv;
    __syncthreads();
    for (int off = 1; off < NC; off <<= 1) {
        int v = (t >= off) ? tmp[t - off] : 0;
        __syncthreads();
        tmp[t] += v;
        __syncthreads();
    }
    int* gsd = half ? gs_b : gs_f;
    int* cur = half ? cur_b : cur_f;
    int excl = tmp[t] - cv;
    gsd[t] = excl;
    cur[t] = excl;
    if (t == NC - 1) gsd[NC] = tmp[t];
}

// sorted points stored as float4 (pad) -> one dwordx4 load per candidate
__global__ __launch_bounds__(256) void scatter_pts_kernel(
    const float* __restrict__ pos, const float* __restrict__ box,
    int* __restrict__ cur_f, int* __restrict__ cur_b,
    float* __restrict__ spf, int* __restrict__ sif,
    float* __restrict__ spb, int* __restrict__ sib)
{
    int t = blockIdx.x * blockDim.x + threadIdx.x;
    if (t < NQ) {
        float x = pos[t*3], y = pos[t*3+1], z = pos[t*3+2];
        int dst = atomicAdd(&cur_f[cell_of(x,y,z)], 1);
        *reinterpret_cast<float4*>(spf + (size_t)dst*4) = make_float4(x, y, z, 0.f);
        sif[dst] = t;
    } else if (t < NQ + NB) {
        int b = t - NQ;
        float x = box[b*3], y = box[b*3+1], z = box[b*3+2];
        int dst = atomicAdd(&cur_b[cell_of(x,y,z)], 1);
        *reinterpret_cast<float4*>(spb + (size_t)dst*4) = make_float4(x, y, z, 0.f);
        sib[dst] = b;
    }
}

// -------- fused: [blocks 0..PREPB) heavy prep  |  [PREPB..) neighbor search --
// Search is pipelined: all 9 row spans loaded up front, segment-0 candidates of
// ALL rows preloaded into registers (independent loads issue together), then
// the 9 ballot/compaction steps consume registers -> one exposed load latency
// instead of nine. Rows >64 candidates take the rare tail loop. Coefs computed
// densely in phase 2.
__global__ __launch_bounds__(256) void nn2gc_kernel(
    const float* __restrict__ pos,
    const float* __restrict__ spf, const int* __restrict__ sif, const int* __restrict__ gsf,
    const float* __restrict__ spb, const int* __restrict__ sib, const int* __restrict__ gsb,
    int* __restrict__ f_cnt, int* __restrict__ f_idx, float* __restrict__ f_d2,
    int* __restrict__ f_cell, float* __restrict__ f_coef,
    int* __restrict__ b_cnt, int* __restrict__ b_idx, float* __restrict__ b_d2,
    int* __restrict__ b_cell, float* __restrict__ b_coef,
    // prep args:
    const float* __restrict__ c1w, const float* __restrict__ d1w,
    const float* __restrict__ c2w, const float* __restrict__ d2w,
    const float* __restrict__ c3w, const float* __restrict__ d3w,
    const float* __restrict__ vel, const float* __restrict__ bfeat,
    const float* __restrict__ cfw, const float* __restrict__ cow,
    const float* __restrict__ d0w, const float* __restrict__ d0b,
    unsigned short* __restrict__ Bt1, unsigned short* __restrict__ Bt2,
    unsigned short* __restrict__ G0f, unsigned short* __restrict__ G0b,
    float* __restrict__ W3p, float* __restrict__ x1)
{
    if (blockIdx.x < PREPB) {
        int stride = PREPB * 256;
        int gid = blockIdx.x * 256 + threadIdx.x;
        // G0f[j, c*32+o] = [1,vel_j] . cf_w[c,:,o]   (bf16, 2 o's per iter)
        for (int i = gid; i < NQ * 1024; i += stride) {
            int j = i >> 10, rr = i & 1023, c = rr >> 4, op = (rr & 15) * 2;
            float vx = vel[j*3+0], vy = vel[j*3+1], vz = vel[j*3+2];
            const float* w = cfw + (size_t)c * 128;    // cf_w[c][f][o], f-stride 32
            float s0 = w[op]   + vx*w[32+op]   + vy*w[64+op]   + vz*w[96+op];
            float s1 = w[op+1] + vx*w[32+op+1] + vy*w[64+op+1] + vz*w[96+op+1];
            *reinterpret_cast<unsigned int*>(G0f + (size_t)j * 2048 + c*32 + op) =
                bf16rne(s0) | (bf16rne(s1) << 16);
        }
        // G0b[j, c*32+o] = bfeat_j . co_w[c,:,o]
        for (int i = gid; i < NB * 1024; i += stride) {
            int j = i >> 10, rr = i & 1023, c = rr >> 4, op = (rr & 15) * 2;
            float b0 = bfeat[j*3+0], b1 = bfeat[j*3+1], b2 = bfeat[j*3+2];
            const float* w = cow + (size_t)c * 96;     // co_w[c][f][o], f-stride 32
            float s0 = b0*w[op]   + b1*w[32+op]   + b2*w[64+op];
            float s1 = b0*w[op+1] + b1*w[32+op+1] + b2*w[64+op+1];
            *reinterpret_cast<unsigned int*>(G0b + (size_t)j * 2048 + c*32 + op) =
                bf16rne(s0) | (bf16rne(s1) << 16);
        }
        for (int i = gid; i < NO * 96; i += stride) {   // Bt1[n,f]; n = c*64+o
            int n = i / 96, f = i % 96, c = n >> 6, o = n & 63;
            float v = (c < 64) ? c1w[((size_t)c*96 + f)*64 + o] : d1w[f*64 + o];
            Bt1[i] = (unsigned short)bf16rne(v);
        }
        for (int i = gid; i < NO * 64; i += stride) {
            int n = i / 64, f = i % 64, c = n >> 6, o = n & 63;
            float v = (c < 64) ? c2w[((size_t)c*64 + f)*64 + o] : d2w[f*64 + o];
            Bt2[i] = (unsigned short)bf16rne(v);
        }
        for (int i = gid; i < 64 * 195; i += stride) {   // W3p[f][c*3+o]
            int f = i / 195, r = i % 195, c = r / 3, o = r % 3;
            W3p[i] = (c < 64) ? c3w[(c*64 + f)*3 + o] : d3w[f*3 + o];
        }
        for (int i = gid; i < NQ * 32; i += stride) {    // dense-0 -> x1[:,64:96]
            int n = i >> 5, o = i & 31;
            float acc = d0b[o] + d0w[o]
                      + vel[n*3+0] * d0w[32 + o]
                      + vel[n*3+1] * d0w[64 + o]
                      + vel[n*3+2] * d0w[96 + o];
            x1[n*96 + 64 + o] = acc;
        }
        return;
    }
    int gw = (int)(blockIdx.x - PREPB) * 4 + ((int)threadIdx.x >> 6);
    int lane = threadIdx.x & 63;
    if (gw >= 2 * NQ) return;
    bool isF = gw < NQ;
    int wid = isF ? gw : gw - NQ;
    const float* sp = isF ? spf : spb;
    const int*   si = isF ? sif : sib;
    const int*   gs = isF ? gsf : gsb;
    int*   cnt   = isF ? f_cnt  : b_cnt;
    int*   idxs  = isF ? f_idx  : b_idx;
    float* d2s   = isF ? f_d2   : b_d2;
    int*   cells = isF ? f_cell : b_cell;
    float* coefs = isF ? f_coef : b_coef;
    int    tot   = isF ? NQ : NB;
    float qx = pos[wid*3+0], qy = pos[wid*3+1], qz = pos[wid*3+2];
    int cx = min(max((int)(qx * (float)GS), 0), GS-1);
    int cy = min(max((int)(qy * (float)GS), 0), GS-1);
    int cz = min(max((int)(qz * (float)GS), 0), GS-1);
    int x0 = max(cx-1, 0), x1c = min(cx+1, GS-1);
    int base = wid * K;
    int c = 0;

    auto process = [&](bool hit, int oj, float ddx, float ddy, float ddz, float d2) {
        unsigned long long m = __ballot(hit);
        int pc = __popcll(m);
        if (pc == 0) return;
        if (c + pc <= K) {
            if (hit) {
                int p = c + __popcll(m & ((1ull << lane) - 1ull));
                idxs[base + p] = oj;
                d2s [base + p] = d2;
                float* cf = coefs + (size_t)(base + p) * 8;
                cf[0] = ddx; cf[1] = ddy; cf[2] = ddz;   // deltas; coefs in phase 2
            }
            c += pc;
        } else {
            // rare overflow: keep the K nearest (top_k semantics)
            while (m) {
                int l = __ffsll((unsigned long long)m) - 1;
                m &= m - 1ull;
                float dd = __shfl(d2, l);
                int jv = __shfl(oj, l);
                float ax = __shfl(ddx, l), ay = __shfl(ddy, l), az = __shfl(ddz, l);
                int slot = -1;
                if (c < K) { slot = c; c++; }
                else {
                    float mx = -1.f; int am = 0;
                    for (int s = 0; s < K; ++s) {
                        float v = d2s[base + s];
                        if (v > mx) { mx = v; am = s; }
                    }
                    if (dd < mx) slot = am;
                }
                if (slot >= 0 && lane == 0) {
                    idxs[base + slot] = jv;
                    d2s [base + slot] = dd;
                    float* cf = coefs + (size_t)(base + slot) * 8;
                    cf[0] = ax; cf[1] = ay; cf[2] = az;
                }
            }
        }
    };

    // spans of all 9 (z,y) rows -- wave-uniform loads, issued together
    int s0v[9], s1v[9];
#pragma unroll
    for (int r = 0; r < 9; ++r) {
        int z = cz + (r / 3) - 1, y = cy + (r % 3) - 1;
        bool ok = ((unsigned)z < (unsigned)GS) && ((unsigned)y < (unsigned)GS);
        int row = ok ? (z*GS + y)*GS : 0;
        int a0 = gs[row + x0];
        int a1 = gs[row + x1c + 1];
        s0v[r] = a0;
        s1v[r] = ok ? a1 : a0;
    }
    // preload segment-0 candidate of every row (independent -> all in flight)
    int    ojv[9];
    float4 pv [9];
#pragma unroll
    for (int r = 0; r < 9; ++r) {
        int a = min(s0v[r] + lane, tot - 1);
        ojv[r] = si[a];
        pv [r] = *reinterpret_cast<const float4*>(sp + (size_t)a * 4);
    }
    // process the 9 rows from registers
#pragma unroll
    for (int r = 0; r < 9; ++r) {
        int ii = s0v[r] + lane;
        float ddx = pv[r].x - qx, ddy = pv[r].y - qy, ddz = pv[r].z - qz;
        float d2 = ddx*ddx + ddy*ddy + ddz*ddz;
        int oj = ojv[r];
        bool hit = (ii < s1v[r]) && (d2 <= R2) && !(isF && oj == wid);
        process(hit, oj, ddx, ddy, ddz, d2);
    }
    // rare tails: rows with more than 64 candidates
#pragma unroll
    for (int r = 0; r < 9; ++r) {
        for (int j0 = s0v[r] + 64; j0 < s1v[r]; j0 += 64) {
            int ii = j0 + lane;
            int a = min(ii, tot - 1);
            int oj = si[a];
            float4 p = *reinterpret_cast<const float4*>(sp + (size_t)a * 4);
            float ddx = p.x - qx, ddy = p.y - qy, ddz = p.z - qz;
            float d2 = ddx*ddx + ddy*ddy + ddz*ddz;
            bool hit = (ii < s1v[r]) && (d2 <= R2) && !(isF && oj == wid);
            process(hit, oj, ddx, ddy, ddz, d2);
        }
    }
    // phase 2: dense coef computation (one pass, all lanes active)
    for (int k2 = lane; k2 < c; k2 += 64) {
        const float4 d = *reinterpret_cast<const float4*>(coefs + (size_t)(base + k2) * 8);
        coef_compute(d.x, d.y, d.z, base + k2, cells, coefs);
    }
    if (lane == 0) cnt[wid] = c;
}

// ---- layer-0 gather (G-form): one block per query, 4 waves, two 32-lane
//      halves process 2 neighbors/iter. jcb = j*2048 + cell*32 precomputed. ---
__global__ __launch_bounds__(256) void gather0_kernel(
    const int* __restrict__ order,
    const int* __restrict__ f_cnt, const int* __restrict__ f_idx,
    const int* __restrict__ f_cell, const float* __restrict__ f_coef,
    const int* __restrict__ b_cnt, const int* __restrict__ b_idx,
    const int* __restrict__ b_cell, const float* __restrict__ b_coef,
    const unsigned short* __restrict__ G0f, const unsigned short* __restrict__ G0b,
    const float* __restrict__ cfb, const float* __restrict__ cob,
    float* __restrict__ x1)
{
    __shared__ __align__(16) float coefF[K * 8];
    __shared__ __align__(16) float coefB[K * 8];
    __shared__ int jF[K], jB[K];
    __shared__ float partF[8][32], partB[8][32];
    int lb = (blockIdx.x & 7) * (gridDim.x >> 3) + (blockIdx.x >> 3);  // XCD swizzle
    int tid = threadIdx.x;
    int wv = tid >> 6, lane = tid & 63;
    int h = lane >> 5, o = lane & 31;
    int r = wv * 2 + h;
    int n = order[lb];
    int cnf = f_cnt[n], cnb = b_cnt[n];
    {
        const float4* srcF = (const float4*)(f_coef + (size_t)n * K * 8);
        const float4* srcB = (const float4*)(b_coef + (size_t)n * K * 8);
        for (int i = tid; i < cnf * 2; i += 256) ((float4*)coefF)[i] = srcF[i];
        for (int i = tid; i < cnb * 2; i += 256) ((float4*)coefB)[i] = srcB[i];
        for (int i = tid; i < cnf; i += 256) jF[i] = f_idx[n*K + i] * 2048 + f_cell[n*K + i] * 32;
        for (int i = tid; i < cnb; i += 256) jB[i] = b_idx[n*K + i] * 2048 + b_cell[n*K + i] * 32;
    }
    __syncthreads();
    // c = dx*4+dy*2+dz ; cell = cbse + dz*16 + dy*4 + dx
    float af = 0.f;
#pragma unroll 2
    for (int k = r; k < cnf; k += 8) {
        const unsigned short* Gj = G0f + jF[k] + o;
        float4 cA = *reinterpret_cast<const float4*>(coefF + k*8);
        float4 cB = *reinterpret_cast<const float4*>(coefF + k*8 + 4);
        af += cA.x * bf16f(Gj[ 0 * 32]);
        af += cA.y * bf16f(Gj[16 * 32]);
        af += cA.z * bf16f(Gj[ 4 * 32]);
        af += cA.w * bf16f(Gj[20 * 32]);
        af += cB.x * bf16f(Gj[ 1 * 32]);
        af += cB.y * bf16f(Gj[17 * 32]);
        af += cB.z * bf16f(Gj[ 5 * 32]);
        af += cB.w * bf16f(Gj[21 * 32]);
    }
    float ab = 0.f;
#pragma unroll 2
    for (int k = r; k < cnb; k += 8) {
        const unsigned short* Gj = G0b + jB[k] + o;
        float4 cA = *reinterpret_cast<const float4*>(coefB + k*8);
        float4 cB = *reinterpret_cast<const float4*>(coefB + k*8 + 4);
        ab += cA.x * bf16f(Gj[ 0 * 32]);
        ab += cA.y * bf16f(Gj[16 * 32]);
        ab += cA.z * bf16f(Gj[ 4 * 32]);
        ab += cA.w * bf16f(Gj[20 * 32]);
        ab += cB.x * bf16f(Gj[ 1 * 32]);
        ab += cB.y * bf16f(Gj[17 * 32]);
        ab += cB.z * bf16f(Gj[ 5 * 32]);
        ab += cB.w * bf16f(Gj[21 * 32]);
    }
    partF[r][o] = af;
    partB[r][o] = ab;
    __syncthreads();
    if (tid < 64) {
        int oo = tid & 31;
        if (tid < 32) {
            float s = cfb[oo];
#pragma unroll
            for (int q = 0; q < 8; ++q) s += partF[q][oo];
            x1[(size_t)n * 96 + 32 + oo] = s;      // a_cf -> x1[:,32:64]
        } else {
            float s = cob[oo];
#pragma unroll
            for (int q = 0; q < 8; ++q) s += partB[q][oo];
            x1[(size_t)n * 96 + oo] = s;           // a_co -> x1[:,0:32]
        }
    }
}

// ---- MFMA G-GEMM: G[j, n] = relu(feats[j,:]) . Bt[n,:]  (bf16 in/out) -------
// A-tile staged ONCE per block; loops over NT n-tiles (65 = 13*5).
template<int F>
__global__ __launch_bounds__(256) void gemmGm_kernel(
    const float* __restrict__ feats,            // [M,F] fp32
    const unsigned short* __restrict__ Bt,      // [NO,F] bf16 (n-major)
    unsigned short* __restrict__ G,             // [M,NO] bf16
    int M)
{
    constexpr int NT = 5;
    constexpr int AST = F + 8;
    __shared__ unsigned short As[64 * AST];     // [m][k]
    __shared__ unsigned short Bs[64 * AST];     // [n][k]
    int tid = threadIdx.x, lane = tid & 63, wv = tid >> 6;
    int m0 = blockIdx.x * 64;
    int nt0 = blockIdx.y * NT;
    for (int i = tid; i < 64 * F / 4; i += 256) {
        int m = i / (F / 4), k4 = i % (F / 4);
        int gm = m0 + m; if (gm >= M) gm = M - 1;
        float4 av = *reinterpret_cast<const float4*>(feats + (size_t)gm * F + k4 * 4);
        uint2 ov;
        ov.x = bf16rne(fmaxf(av.x, 0.f)) | (bf16rne(fmaxf(av.y, 0.f)) << 16);
        ov.y = bf16rne(fmaxf(av.z, 0.f)) | (bf16rne(fmaxf(av.w, 0.f)) << 16);
        *reinterpret_cast<uint2*>(As + m * AST + k4 * 4) = ov;
    }
    int mr = lane & 15, quad = lane >> 4;
    for (int t = 0; t < NT; ++t) {
        int no0 = (nt0 + t) * 64;
        __syncthreads();   // waves done reading Bs (t=0: harmless)
        for (int i = tid; i < 64 * F / 8; i += 256) {
            int nn = i / (F / 8), k8 = i % (F / 8);
            *reinterpret_cast<uint4*>(Bs + nn * AST + k8 * 8) =
                *reinterpret_cast<const uint4*>(Bt + (size_t)(no0 + nn) * F + k8 * 8);
        }
        __syncthreads();   // Bs (and As on t=0) visible
        f32x4 acc[4] = {{0.f,0.f,0.f,0.f},{0.f,0.f,0.f,0.f},
                        {0.f,0.f,0.f,0.f},{0.f,0.f,0.f,0.f}};
#pragma unroll
        for (int kc = 0; kc < F; kc += 32) {
            bf16x8 a = *reinterpret_cast<const bf16x8*>(As + (wv*16 + mr) * AST + kc + quad*8);
#pragma unroll
            for (int q = 0; q < 4; ++q) {
                bf16x8 b = *reinterpret_cast<const bf16x8*>(Bs + (q*16 + mr) * AST + kc + quad*8);
                acc[q] = __builtin_amdgcn_mfma_f32_16x16x32_bf16(a, b, acc[q], 0, 0, 0);
            }
        }
        // C layout: col = lane&15, row = quad*4 + reg
#pragma unroll
        for (int q = 0; q < 4; ++q) {
#pragma unroll
            for (int rr = 0; rr < 4; ++rr) {
                int gm = m0 + wv*16 + quad*4 + rr;
                if (gm < M)
                    G[(size_t)gm * NO + no0 + q*16 + mr] = (unsigned short)bf16rne(acc[q][rr]);
            }
        }
    }
}

// ---- G-gather v2: ONE QUERY PER BLOCK, k-loop split across the 4 waves ------
// jcb = j*NO + cell*64 precomputed in LDS (shorter dependent address chain).
// FUSEY=1 additionally fuses Y = relu(x3) * W3p using all 256 threads.
template<int FUSEY>
__global__ __launch_bounds__(256) void gatherG_kernel(
    const int* __restrict__ order,
    const int* __restrict__ cnt, const int* __restrict__ nidx,
    const int* __restrict__ ncell, const float* __restrict__ ncoef,
    const unsigned short* __restrict__ G,
    const float* __restrict__ cb, const float* __restrict__ db,
    const float* __restrict__ resid, float* __restrict__ out,
    const float* __restrict__ W3p, float* __restrict__ Y)
{
    __shared__ __align__(16) float coefL[K * 8];   // 2.5 KB
    __shared__ int jL[K];
    __shared__ float part[3][64];
    __shared__ float xs[64];
    int lb = (blockIdx.x & 7) * (gridDim.x >> 3) + (blockIdx.x >> 3);  // XCD swizzle
    int tid = threadIdx.x;
    int wv = tid >> 6, lane = tid & 63;
    int n = order[lb];
    int cn = cnt[n];
    // cooperative staging: coefs (float4 x 2 per k), combined j*NO+cell*64
    {
        const float4* src = (const float4*)(ncoef + (size_t)n * K * 8);
        float4* dst = (float4*)coefL;
        for (int i = tid; i < cn * 2; i += 256) dst[i] = src[i];
        for (int i = tid; i < cn; i += 256)
            jL[i] = nidx[n*K + i] * NO + ncell[n*K + i] * 64;
    }
    __syncthreads();
    float a0 = 0.f, a1 = 0.f, a2 = 0.f, a3 = 0.f;
#pragma unroll 2
    for (int k = wv; k < cn; k += 4) {
        float4 cA = *reinterpret_cast<const float4*>(coefL + k*8);      // c=0..3 (dx=0)
        float4 cB = *reinterpret_cast<const float4*>(coefL + k*8 + 4);  // c=4..7 (dx=1)
        const unsigned short* Gj = G + jL[k] + lane;
        // c = dx*4+dy*2+dz ; cell = cbse + dz*16 + dy*4 + dx
        a0 += cA.x * bf16f(Gj[ 0 * 64]);
        a1 += cA.y * bf16f(Gj[16 * 64]);
        a2 += cA.z * bf16f(Gj[ 4 * 64]);
        a3 += cA.w * bf16f(Gj[20 * 64]);
        a0 += cB.x * bf16f(Gj[ 1 * 64]);
        a1 += cB.y * bf16f(Gj[17 * 64]);
        a2 += cB.z * bf16f(Gj[ 5 * 64]);
        a3 += cB.w * bf16f(Gj[21 * 64]);
    }
    float s = (a0 + a1) + (a2 + a3);
    if (wv > 0) part[wv - 1][lane] = s;
    __syncthreads();
    if (wv == 0) {
        float acc = cb[lane] + db[lane] + s
                  + part[0][lane] + part[1][lane] + part[2][lane];
        acc += bf16f(G[(size_t)n * NO + 64*64 + lane]);   // dense skip
        if (resid) acc += resid[(size_t)n * 64 + lane];
        if (!FUSEY) {
            out[(size_t)n * 64 + lane] = acc;
        } else {
            xs[lane] = fmaxf(acc, 0.f);
        }
    }
    if (FUSEY) {
        __syncthreads();
        // fused y3t: Y[n, t] = sum_f relu(x3[n,f]) * W3p[f,t]   (t < 195)
        for (int t = tid; t < 195; t += 256) {
            float sum = 0.f;
#pragma unroll 16
            for (int f = 0; f < 64; ++f) sum += xs[f] * W3p[f*195 + t];
            Y[(size_t)n * 195 + t] = sum;
        }
    }
}

__global__ __launch_bounds__(256) void gather3_kernel(
    const int* __restrict__ order,
    const int* __restrict__ cnt, const int* __restrict__ nidx,
    const int* __restrict__ ncell, const float* __restrict__ ncoef,
    const float* __restrict__ Y,
    const float* __restrict__ cb3, const float* __restrict__ db3,
    float* __restrict__ out)
{
    int lb = (blockIdx.x & 7) * (gridDim.x >> 3) + (blockIdx.x >> 3);
    int gw = lb * 4 + ((int)threadIdx.x >> 6);
    int lane = threadIdx.x & 63;
    if (gw >= NQ) return;
    int n = order[gw];
    int cn = cnt[n];
    float a0 = 0.f, a1 = 0.f, a2 = 0.f;
#pragma unroll
    for (int seg = 0; seg < 2; ++seg) {
        int kidx = seg * 64 + lane;
        if (kidx < cn) {
            int j  = nidx [n*K + kidx];
            int cb = ncell[n*K + kidx];
            const float* cf = ncoef + (size_t)(n*K + kidx) * 8;
            const float* Yj = Y + (size_t)j * 195;
#pragma unroll
            for (int c = 0; c < 8; ++c) {
                int cell = cb + (c & 1)*16 + ((c >> 1) & 1)*4 + (c >> 2);
                float wgt = cf[c];
                const float* Tp = Yj + cell*3;
                a0 += wgt * Tp[0];
                a1 += wgt * Tp[1];
                a2 += wgt * Tp[2];
            }
        }
    }
#pragma unroll
    for (int s = 32; s > 0; s >>= 1) {
        a0 += __shfl_down(a0, s);
        a1 += __shfl_down(a1, s);
        a2 += __shfl_down(a2, s);
    }
    if (lane == 0) {
        const float* Yn = Y + (size_t)n * 195 + 192;   // dense skip (c=64)
        out[n*3+0] = (a0 + Yn[0] + cb3[0] + db3[0]) * (1.f/128.f);
        out[n*3+1] = (a1 + Yn[1] + cb3[1] + db3[1]) * (1.f/128.f);
        out[n*3+2] = (a2 + Yn[2] + cb3[2] + db3[2]) * (1.f/128.f);
    }
}

} // namespace

extern "C" void kernel_launch(void* const* d_in, const int* in_sizes, int n_in,
                              void* d_out, int out_size, void* d_ws, size_t ws_size,
                              hipStream_t stream)
{
    const float* pos       = (const float*)d_in[0];
    const float* vel       = (const float*)d_in[1];
    const float* box       = (const float*)d_in[2];
    const float* box_feats = (const float*)d_in[3];
    const float* cf_w = (const float*)d_in[4];  const float* cf_b = (const float*)d_in[5];
    const float* co_w = (const float*)d_in[6];  const float* co_b = (const float*)d_in[7];
    const float* d0_w = (const float*)d_in[8];  const float* d0_b = (const float*)d_in[9];
    const float* c1_w = (const float*)d_in[10]; const float* c1_b = (const float*)d_in[11];
    const float* d1_w = (const float*)d_in[12]; const float* d1_b = (const float*)d_in[13];
    const float* c2_w = (const float*)d_in[14]; const float* c2_b = (const float*)d_in[15];
    const float* d2_w = (const float*)d_in[16]; const float* d2_b = (const float*)d_in[17];
    const float* c3_w = (const float*)d_in[18]; const float* c3_b = (const float*)d_in[19];
    const float* d3_w = (const float*)d_in[20]; const float* d3_b = (const float*)d_in[21];

    char* wsb = (char*)d_ws;
    size_t off = 0;
    auto alloc = [&](size_t bytes) {
        void* p = wsb + off;
        off = (off + bytes + 255) & ~(size_t)255;
        return p;
    };
    // Big region time-shared:
    //   [0, 3.84 MB)  : {f_d2, b_d2} during nn2gc
    //   [4 MB, 28.6)  : G0f (layer-0 fluid G-form)   -- written by fused prep,
    //   [32 MB, 44.3) : G0b (layer-0 box G-form)        consumed by gather0
    //   whole region  : bf16 G rows for layers 1/2 (overwrites G0 afterwards)
    char*  Graw = (char*)alloc((size_t)NQ * NO * 2 + 4096);   // 50 MB
    unsigned short* G = (unsigned short*)Graw;
    float* f_d2 = (float*)Graw;
    float* b_d2 = (float*)Graw + (size_t)NQ * K;
    unsigned short* G0f = (unsigned short*)(Graw + ((size_t)4 << 20));
    unsigned short* G0b = (unsigned short*)(Graw + ((size_t)32 << 20));
    int*   f_cnt  = (int*)  alloc((size_t)NQ * 4);
    int*   f_idx  = (int*)  alloc((size_t)NQ * K * 4);
    int*   f_cell = (int*)  alloc((size_t)NQ * K * 4);
    float* f_coef = (float*)alloc((size_t)NQ * K * 8 * 4);
    int*   b_cnt  = (int*)  alloc((size_t)NQ * 4);
    int*   b_idx  = (int*)  alloc((size_t)NQ * K * 4);
    int*   b_cell = (int*)  alloc((size_t)NQ * K * 4);
    float* b_coef = (float*)alloc((size_t)NQ * K * 8 * 4);
    float* x1     = (float*)alloc((size_t)NQ * 96 * 4);
    float* x2     = (float*)alloc((size_t)NQ * 64 * 4);
    unsigned short* Bt1 = (unsigned short*)alloc((size_t)NO * 96 * 2);  // 0.8 MB
    unsigned short* Bt2 = (unsigned short*)alloc((size_t)NO * 64 * 2);  // 0.5 MB
    float* W3p    = (float*)alloc((size_t)64 * 195 * 4);
    float* Y      = (float*)alloc((size_t)NQ * 195 * 4);
    // grid structures
    int*   gs_f   = (int*)  alloc((size_t)(NC + 1) * 4);
    int*   gs_b   = (int*)  alloc((size_t)(NC + 1) * 4);
    int*   cur_f  = (int*)  alloc((size_t)NC * 4);
    int*   cur_b  = (int*)  alloc((size_t)NC * 4);
    float* spf    = (float*)alloc((size_t)(NQ + 1) * 4 * 4);
    int*   sif    = (int*)  alloc((size_t)NQ * 4);
    float* spb    = (float*)alloc((size_t)(NB + 1) * 4 * 4);
    int*   sib    = (int*)  alloc((size_t)NB * 4);

    dim3 b256(256);
    // 1. count + scan (single block, LDS-only)
    grid_build_kernel<<<1, 1024, 0, stream>>>(pos, box, gs_f, gs_b, cur_f, cur_b);
    // 2. reorder points into cell-sorted arrays (float4-padded)
    scatter_pts_kernel<<<(NQ + NB + 255)/256, b256, 0, stream>>>(
        pos, box, cur_f, cur_b, spf, sif, spb, sib);
    // 3. fused: pipelined neighbor search || heavy prep (G0, Bt, W3p, dense-0)
    nn2gc_kernel<<<PREPB + (2*NQ + 3)/4, b256, 0, stream>>>(
        pos, spf, sif, gs_f, spb, sib, gs_b,
        f_cnt, f_idx, f_d2, f_cell, f_coef,
        b_cnt, b_idx, b_d2, b_cell, b_coef,
        c1_w, d1_w, c2_w, d2_w, c3_w, d3_w,
        vel, box_feats, cf_w, co_w, d0_w, d0_b,
        Bt1, Bt2, G0f, G0b, W3p, x1);
    // 4. layer 0: G-form gather writes x1[:,0:64] (biases fused)
    gather0_kernel<<<NQ, b256, 0, stream>>>(sif,
        f_cnt, f_idx, f_cell, f_coef,
        b_cnt, b_idx, b_cell, b_coef,
        G0f, G0b, cf_b, co_b, x1);
    // 5. layer 1: G1 = relu(x1) x [c1;d1] (MFMA) ; x2 = gather(G1) + biases
    gemmGm_kernel<96><<<dim3((NQ+63)/64, 13), b256, 0, stream>>>(x1, Bt1, G, NQ);
    gatherG_kernel<0><<<NQ, b256, 0, stream>>>(sif, f_cnt, f_idx, f_cell, f_coef,
        G, c1_b, d1_b, nullptr, x2, nullptr, nullptr);
    // 6. layer 2: G2 = relu(x2) x [c2;d2] (MFMA) ;
    //    fused: x3 = gather + biases + x2 ; Y = relu(x3) * [c3;d3]
    gemmGm_kernel<64><<<dim3((NQ+63)/64, 13), b256, 0, stream>>>(x2, Bt2, G, NQ);
    gatherG_kernel<1><<<NQ, b256, 0, stream>>>(sif, f_cnt, f_idx, f_cell, f_coef,
        G, c2_b, d2_b, x2, nullptr, W3p, Y);
    // 7. layer 3 gather (O=3)
    gather3_kernel<<<NBLK8, b256, 0, stream>>>(sif, f_cnt, f_idx, f_cell, f_coef,
        Y, c3_b, d3_b, (float*)d_out);

    (void)in_sizes; (void)n_in; (void)out_size; (void)ws_size;
    (void)f_d2; (void)b_d2;
}